// Round 1
// baseline (662.020 us; speedup 1.0000x reference)
//
#include <hip/hip_runtime.h>
#include <math.h>

#define NN 100000
#define NE 1600000
#define FI 128
#define FH 64
#define FO 16

// ---- edge dtype detection: int64 (reference) vs int32 (harness may narrow) ----
__global__ void k_detect(const int* __restrict__ edges, int* __restrict__ mode) {
    if (blockIdx.x == 0 && threadIdx.x == 0) {
        unsigned orv = 0;
        for (int i = 0; i < 16; ++i) orv |= (unsigned)edges[2 * i + 1];
        *mode = (orv == 0u) ? 1 : 0;  // 1 = int64 (odd words are high halves == 0)
    }
}

__global__ void k_cvt(const void* __restrict__ edges, int* __restrict__ s32,
                      int* __restrict__ d32, const int* __restrict__ mode) {
    int e = blockIdx.x * blockDim.x + threadIdx.x;
    if (e >= NE) return;
    if (*mode) {
        const long long* p = (const long long*)edges;
        s32[e] = (int)p[e];
        d32[e] = (int)p[NE + e];
    } else {
        const int* p = (const int*)edges;
        s32[e] = p[e];
        d32[e] = p[NE + e];
    }
}

// ---- degree / dinv ----
__global__ void k_deg(const int* __restrict__ d32, unsigned* __restrict__ cnt) {
    int e = blockIdx.x * blockDim.x + threadIdx.x;
    if (e < NE) atomicAdd(&cnt[d32[e]], 1u);
}

__global__ void k_dinv(const unsigned* __restrict__ cnt, float* __restrict__ dinv) {
    int v = blockIdx.x * blockDim.x + threadIdx.x;
    if (v < NN) dinv[v] = rsqrtf((float)(1u + cnt[v]));  // +1 = self loop
}

// ---- GEMM1: [NN,128] @ [128,64] ; wave = 4 nodes, lane = out col ----
__global__ __launch_bounds__(256) void k_gemm1(const float* __restrict__ x,
                                               const float* __restrict__ W,
                                               float* __restrict__ h) {
    __shared__ float Wl[FI * FH];
    {
        const float4* W4 = (const float4*)W;
        float4* Wl4 = (float4*)Wl;
        for (int i = threadIdx.x; i < FI * FH / 4; i += 256) Wl4[i] = W4[i];
    }
    __syncthreads();
    int wave = (blockIdx.x * 256 + threadIdx.x) >> 6;
    int lane = threadIdx.x & 63;
    int node0 = wave * 4;
    if (node0 >= NN) return;
    float acc0 = 0.f, acc1 = 0.f, acc2 = 0.f, acc3 = 0.f;
    for (int k4 = 0; k4 < FI / 4; ++k4) {
        float4 x0 = *(const float4*)&x[(node0 + 0) * FI + k4 * 4];
        float4 x1 = *(const float4*)&x[(node0 + 1) * FI + k4 * 4];
        float4 x2 = *(const float4*)&x[(node0 + 2) * FI + k4 * 4];
        float4 x3 = *(const float4*)&x[(node0 + 3) * FI + k4 * 4];
#pragma unroll
        for (int kk = 0; kk < 4; ++kk) {
            float w = Wl[(k4 * 4 + kk) * FH + lane];
            acc0 += (&x0.x)[kk] * w;
            acc1 += (&x1.x)[kk] * w;
            acc2 += (&x2.x)[kk] * w;
            acc3 += (&x3.x)[kk] * w;
        }
    }
    h[(node0 + 0) * FH + lane] = acc0;
    h[(node0 + 1) * FH + lane] = acc1;
    h[(node0 + 2) * FH + lane] = acc2;
    h[(node0 + 3) * FH + lane] = acc3;
}

// ---- aggregate layer1: one wave per edge, lane = feature ----
__global__ __launch_bounds__(256) void k_agg1(const int* __restrict__ s32, const int* __restrict__ d32,
                                              const float* __restrict__ dinv,
                                              const float* __restrict__ h,
                                              float* __restrict__ agg) {
    int wave = (blockIdx.x * 256 + threadIdx.x) >> 6;
    int lane = threadIdx.x & 63;
    if (wave >= NE) return;
    int s = s32[wave], d = d32[wave];
    float norm = dinv[s] * dinv[d];
    atomicAdd(&agg[d * FH + lane], h[s * FH + lane] * norm);
}

// ---- bias + self-loop + relu (in place on agg) ----
__global__ __launch_bounds__(256) void k_post1(float* __restrict__ agg,
                                               const float* __restrict__ hpre,
                                               const float* __restrict__ dinv,
                                               const float* __restrict__ b) {
    int t = blockIdx.x * 256 + threadIdx.x;  // = v*64 + j
    int v = t >> 6, j = t & 63;
    if (v >= NN) return;
    float di = dinv[v];
    float val = agg[t] + hpre[t] * di * di + b[j];
    agg[t] = fmaxf(val, 0.f);
}

// ---- GEMM2: [NN,64] @ [64,16] ; wave = 4 nodes, 16 lanes per node ----
__global__ __launch_bounds__(256) void k_gemm2(const float* __restrict__ h1,
                                               const float* __restrict__ W,
                                               float* __restrict__ h2) {
    __shared__ float Wl[FH * FO];
    for (int i = threadIdx.x; i < FH * FO / 4; i += 256) ((float4*)Wl)[i] = ((const float4*)W)[i];
    __syncthreads();
    int wave = (blockIdx.x * 256 + threadIdx.x) >> 6;
    int sub = (threadIdx.x & 63) >> 4;
    int j = threadIdx.x & 15;
    int node = wave * 4 + sub;
    if (node >= NN) return;
    float acc = 0.f;
    for (int k4 = 0; k4 < FH / 4; ++k4) {
        float4 hv = *(const float4*)&h1[node * FH + k4 * 4];
#pragma unroll
        for (int kk = 0; kk < 4; ++kk) acc += (&hv.x)[kk] * Wl[(k4 * 4 + kk) * FO + j];
    }
    h2[node * FO + j] = acc;
}

// ---- aggregate layer2: 16 lanes per edge ----
__global__ __launch_bounds__(256) void k_agg2(const int* __restrict__ s32, const int* __restrict__ d32,
                                              const float* __restrict__ dinv,
                                              const float* __restrict__ h2,
                                              float* __restrict__ agg) {
    int t = blockIdx.x * 256 + threadIdx.x;
    int e = t >> 4, j = t & 15;
    if (e >= NE) return;
    int s = s32[e], d = d32[e];
    float norm = dinv[s] * dinv[d];
    atomicAdd(&agg[d * FO + j], h2[s * FO + j] * norm);
}

// ---- bias + self-loop + log_softmax, in place on d_out ----
__global__ __launch_bounds__(256) void k_final(float* __restrict__ agg,
                                               const float* __restrict__ hpre,
                                               const float* __restrict__ dinv,
                                               const float* __restrict__ b) {
    int v = blockIdx.x * 256 + threadIdx.x;
    if (v >= NN) return;
    float di = dinv[v];
    float di2 = di * di;
    float vals[FO];
    float m = -INFINITY;
#pragma unroll
    for (int j = 0; j < FO; ++j) {
        float xv = agg[v * FO + j] + hpre[v * FO + j] * di2 + b[j];
        vals[j] = xv;
        m = fmaxf(m, xv);
    }
    float ssum = 0.f;
#pragma unroll
    for (int j = 0; j < FO; ++j) ssum += expf(vals[j] - m);
    float lse = m + logf(ssum);
#pragma unroll
    for (int j = 0; j < FO; ++j) agg[v * FO + j] = vals[j] - lse;
}

extern "C" void kernel_launch(void* const* d_in, const int* in_sizes, int n_in,
                              void* d_out, int out_size, void* d_ws, size_t ws_size,
                              hipStream_t stream) {
    const float* x = (const float*)d_in[0];
    const void* edges = d_in[1];
    const float* W1 = (const float*)d_in[2];
    const float* b1 = (const float*)d_in[3];
    const float* W2 = (const float*)d_in[4];
    const float* b2 = (const float*)d_in[5];
    float* out = (float*)d_out;

    char* ws = (char*)d_ws;
    size_t off = 0;
    auto take = [&](size_t bytes) {
        void* p = ws + off;
        off += (bytes + 255) & ~(size_t)255;
        return p;
    };
    int* mode = (int*)take(256);
    int* s32 = (int*)take((size_t)NE * 4);
    int* d32 = (int*)take((size_t)NE * 4);
    unsigned* cnt = (unsigned*)take((size_t)NN * 4);
    float* dinv = (float*)take((size_t)NN * 4);
    float* h1p = (float*)take((size_t)NN * FH * 4);
    float* h1 = (float*)take((size_t)NN * FH * 4);  // agg1 buffer, then h1 in place
    float* h2p = (float*)take((size_t)NN * FO * 4);

    hipMemsetAsync(cnt, 0, (size_t)NN * 4, stream);
    hipMemsetAsync(h1, 0, (size_t)NN * FH * 4, stream);
    hipMemsetAsync(d_out, 0, (size_t)NN * FO * 4, stream);

    k_detect<<<1, 64, 0, stream>>>((const int*)edges, mode);
    k_cvt<<<(NE + 255) / 256, 256, 0, stream>>>(edges, s32, d32, mode);
    k_deg<<<(NE + 255) / 256, 256, 0, stream>>>(d32, cnt);
    k_dinv<<<(NN + 255) / 256, 256, 0, stream>>>(cnt, dinv);
    k_gemm1<<<(NN / 4 * 64) / 256, 256, 0, stream>>>(x, W1, h1p);
    k_agg1<<<(size_t)NE * 64 / 256, 256, 0, stream>>>(s32, d32, dinv, h1p, h1);
    k_post1<<<(size_t)NN * FH / 256, 256, 0, stream>>>(h1, h1p, dinv, b1);
    k_gemm2<<<(NN / 4 * 64) / 256, 256, 0, stream>>>(h1, W2, h2p);
    k_agg2<<<(size_t)NE * FO / 256, 256, 0, stream>>>(s32, d32, dinv, h2p, out);
    k_final<<<(NN + 255) / 256, 256, 0, stream>>>(out, h2p, dinv, b2);
}

// Round 2
// 434.367 us; speedup vs baseline: 1.5241x; 1.5241x over previous
//
#include <hip/hip_runtime.h>
#include <math.h>

#define NN 100000
#define NE 1600000
#define FI 128
#define FH 64
#define FO 16
#define NBLK ((NN + 255) / 256)  // 391

// ---- edge dtype detection: int64 (reference) vs int32 ----
__global__ void k_detect(const int* __restrict__ edges, int* __restrict__ mode) {
    if (blockIdx.x == 0 && threadIdx.x == 0) {
        unsigned orv = 0;
        for (int i = 0; i < 16; ++i) orv |= (unsigned)edges[2 * i + 1];
        *mode = (orv == 0u) ? 1 : 0;  // 1 = int64
    }
}

__device__ __forceinline__ void load_edge(const int* edges, int mode, int e, int& s, int& d) {
    if (mode) { s = edges[2 * e]; d = edges[2 * (NE + e)]; }
    else      { s = edges[e];     d = edges[NE + e]; }
}

// ---- degree count ----
__global__ void k_deg(const int* __restrict__ edges, const int* __restrict__ mode,
                      unsigned* __restrict__ cnt) {
    int e = blockIdx.x * blockDim.x + threadIdx.x;
    if (e >= NE) return;
    int s, d;
    load_edge(edges, *mode, e, s, d);
    atomicAdd(&cnt[d], 1u);
}

__global__ void k_dinv(const unsigned* __restrict__ cnt, float* __restrict__ dinv) {
    int v = blockIdx.x * blockDim.x + threadIdx.x;
    if (v < NN) dinv[v] = rsqrtf((float)(1u + cnt[v]));  // +1 self loop
}

// ---- exclusive scan of cnt -> rowstart (3 kernels) ----
__global__ void k_scan1(const unsigned* __restrict__ cnt, unsigned* __restrict__ rowstart,
                        unsigned* __restrict__ bsum) {
    __shared__ unsigned tmp[256];
    int v = blockIdx.x * 256 + threadIdx.x;
    unsigned x = (v < NN) ? cnt[v] : 0u;
    tmp[threadIdx.x] = x;
    __syncthreads();
    for (int ofs = 1; ofs < 256; ofs <<= 1) {
        unsigned t = (threadIdx.x >= (unsigned)ofs) ? tmp[threadIdx.x - ofs] : 0u;
        __syncthreads();
        tmp[threadIdx.x] += t;
        __syncthreads();
    }
    if (v < NN) rowstart[v] = tmp[threadIdx.x] - x;  // exclusive within block
    if (threadIdx.x == 255) bsum[blockIdx.x] = tmp[255];
}

__global__ void k_scan2(unsigned* __restrict__ bsum) {
    __shared__ unsigned tmp[512];
    int t = threadIdx.x;
    unsigned x = (t < NBLK) ? bsum[t] : 0u;
    tmp[t] = x;
    __syncthreads();
    for (int ofs = 1; ofs < 512; ofs <<= 1) {
        unsigned v = (t >= ofs) ? tmp[t - ofs] : 0u;
        __syncthreads();
        tmp[t] += v;
        __syncthreads();
    }
    if (t < NBLK) bsum[t] = tmp[t] - x;  // exclusive block offsets
}

__global__ void k_scan3(unsigned* __restrict__ rowstart, const unsigned* __restrict__ bsum) {
    int v = blockIdx.x * 256 + threadIdx.x;
    if (v < NN) rowstart[v] += bsum[blockIdx.x];
    if (v == 0) rowstart[NN] = NE;
}

// ---- counting-sort scatter: bucket edges by dst, precompute norm ----
__global__ void k_scatter(const int* __restrict__ edges, const int* __restrict__ mode,
                          const float* __restrict__ dinv, const unsigned* __restrict__ rowstart,
                          unsigned* __restrict__ cur, int* __restrict__ esrc,
                          float* __restrict__ enorm) {
    int e = blockIdx.x * blockDim.x + threadIdx.x;
    if (e >= NE) return;
    int s, d;
    load_edge(edges, *mode, e, s, d);
    unsigned pos = rowstart[d] + atomicAdd(&cur[d], 1u);
    esrc[pos] = s;
    enorm[pos] = dinv[s] * dinv[d];
}

// ---- GEMM1: [NN,128] @ [128,64] ; wave = 4 nodes, lane = out col ----
__global__ __launch_bounds__(256) void k_gemm1(const float* __restrict__ x,
                                               const float* __restrict__ W,
                                               float* __restrict__ h) {
    __shared__ float Wl[FI * FH];
    {
        const float4* W4 = (const float4*)W;
        float4* Wl4 = (float4*)Wl;
        for (int i = threadIdx.x; i < FI * FH / 4; i += 256) Wl4[i] = W4[i];
    }
    __syncthreads();
    int wave = (blockIdx.x * 256 + threadIdx.x) >> 6;
    int lane = threadIdx.x & 63;
    int node0 = wave * 4;
    if (node0 >= NN) return;
    float acc0 = 0.f, acc1 = 0.f, acc2 = 0.f, acc3 = 0.f;
    for (int k4 = 0; k4 < FI / 4; ++k4) {
        float4 x0 = *(const float4*)&x[(node0 + 0) * FI + k4 * 4];
        float4 x1 = *(const float4*)&x[(node0 + 1) * FI + k4 * 4];
        float4 x2 = *(const float4*)&x[(node0 + 2) * FI + k4 * 4];
        float4 x3 = *(const float4*)&x[(node0 + 3) * FI + k4 * 4];
#pragma unroll
        for (int kk = 0; kk < 4; ++kk) {
            float w = Wl[(k4 * 4 + kk) * FH + lane];
            acc0 += (&x0.x)[kk] * w;
            acc1 += (&x1.x)[kk] * w;
            acc2 += (&x2.x)[kk] * w;
            acc3 += (&x3.x)[kk] * w;
        }
    }
    h[(node0 + 0) * FH + lane] = acc0;
    h[(node0 + 1) * FH + lane] = acc1;
    h[(node0 + 2) * FH + lane] = acc2;
    h[(node0 + 3) * FH + lane] = acc3;
}

// ---- layer1 aggregate (pull/CSR) + bias + self-loop + relu, fused ----
__global__ __launch_bounds__(256) void k_gather1(const unsigned* __restrict__ rowstart,
                                                 const int* __restrict__ esrc,
                                                 const float* __restrict__ enorm,
                                                 const float* __restrict__ h1p,
                                                 const float* __restrict__ dinv,
                                                 const float* __restrict__ b,
                                                 float* __restrict__ h1out) {
    int v = (blockIdx.x * 256 + threadIdx.x) >> 6;
    int lane = threadIdx.x & 63;
    if (v >= NN) return;
    unsigned beg = rowstart[v], end = rowstart[v + 1];
    float acc = 0.f;
    unsigned i = beg;
    for (; i + 1 < end; i += 2) {
        int s0 = esrc[i], s1 = esrc[i + 1];
        float n0 = enorm[i], n1 = enorm[i + 1];
        float a0 = h1p[s0 * FH + lane];
        float a1 = h1p[s1 * FH + lane];
        acc += a0 * n0 + a1 * n1;
    }
    if (i < end) acc += h1p[esrc[i] * FH + lane] * enorm[i];
    float di = dinv[v];
    float val = acc + h1p[v * FH + lane] * di * di + b[lane];
    h1out[v * FH + lane] = fmaxf(val, 0.f);
}

// ---- GEMM2: [NN,64] @ [64,16] ----
__global__ __launch_bounds__(256) void k_gemm2(const float* __restrict__ h1,
                                               const float* __restrict__ W,
                                               float* __restrict__ h2) {
    __shared__ float Wl[FH * FO];
    for (int i = threadIdx.x; i < FH * FO / 4; i += 256) ((float4*)Wl)[i] = ((const float4*)W)[i];
    __syncthreads();
    int wave = (blockIdx.x * 256 + threadIdx.x) >> 6;
    int sub = (threadIdx.x & 63) >> 4;
    int j = threadIdx.x & 15;
    int node = wave * 4 + sub;
    if (node >= NN) return;
    float acc = 0.f;
    for (int k4 = 0; k4 < FH / 4; ++k4) {
        float4 hv = *(const float4*)&h1[node * FH + k4 * 4];
#pragma unroll
        for (int kk = 0; kk < 4; ++kk) acc += (&hv.x)[kk] * Wl[(k4 * 4 + kk) * FO + j];
    }
    h2[node * FO + j] = acc;
}

// ---- layer2 aggregate (pull/CSR) + bias + self-loop + log_softmax, fused ----
// wave = 1 node; 4 edge-groups x 16 features
__global__ __launch_bounds__(256) void k_gather2(const unsigned* __restrict__ rowstart,
                                                 const int* __restrict__ esrc,
                                                 const float* __restrict__ enorm,
                                                 const float* __restrict__ h2p,
                                                 const float* __restrict__ dinv,
                                                 const float* __restrict__ b,
                                                 float* __restrict__ out) {
    int v = (blockIdx.x * 256 + threadIdx.x) >> 6;
    int lane = threadIdx.x & 63;
    int g = lane >> 4, j = lane & 15;
    if (v >= NN) return;
    unsigned beg = rowstart[v], end = rowstart[v + 1];
    float acc = 0.f;
    for (unsigned i = beg + g; i < end; i += 4) {
        acc += h2p[esrc[i] * FO + j] * enorm[i];
    }
    acc += __shfl_xor(acc, 16);
    acc += __shfl_xor(acc, 32);
    float di = dinv[v];
    float val = acc + h2p[v * FO + j] * di * di + b[j];
    // log-softmax across the 16 features (lanes j within 16-lane group; all groups identical)
    float m = val;
#pragma unroll
    for (int w = 1; w < 16; w <<= 1) m = fmaxf(m, __shfl_xor(m, w));
    float ex = expf(val - m);
    float ssum = ex;
#pragma unroll
    for (int w = 1; w < 16; w <<= 1) ssum += __shfl_xor(ssum, w);
    float res = val - (m + logf(ssum));
    if (g == 0) out[v * FO + j] = res;
}

extern "C" void kernel_launch(void* const* d_in, const int* in_sizes, int n_in,
                              void* d_out, int out_size, void* d_ws, size_t ws_size,
                              hipStream_t stream) {
    const float* x = (const float*)d_in[0];
    const int* edges = (const int*)d_in[1];
    const float* W1 = (const float*)d_in[2];
    const float* b1 = (const float*)d_in[3];
    const float* W2 = (const float*)d_in[4];
    const float* b2 = (const float*)d_in[5];
    float* out = (float*)d_out;

    char* ws = (char*)d_ws;
    size_t off = 0;
    auto take = [&](size_t bytes) {
        void* p = ws + off;
        off += (bytes + 255) & ~(size_t)255;
        return p;
    };
    int* mode = (int*)take(256);
    unsigned* cnt = (unsigned*)take((size_t)NN * 4);       // degree, then reused as cursor
    float* dinv = (float*)take((size_t)NN * 4);
    unsigned* rowstart = (unsigned*)take((size_t)(NN + 1) * 4);
    unsigned* bsum = (unsigned*)take((size_t)NBLK * 4);
    int* esrc = (int*)take((size_t)NE * 4);
    float* enorm = (float*)take((size_t)NE * 4);
    float* h1p = (float*)take((size_t)NN * FH * 4);
    float* h1 = (float*)take((size_t)NN * FH * 4);
    float* h2p = (float*)take((size_t)NN * FO * 4);

    hipMemsetAsync(cnt, 0, (size_t)NN * 4, stream);
    k_detect<<<1, 64, 0, stream>>>(edges, mode);
    k_deg<<<(NE + 255) / 256, 256, 0, stream>>>(edges, mode, cnt);
    k_dinv<<<(NN + 255) / 256, 256, 0, stream>>>(cnt, dinv);
    k_scan1<<<NBLK, 256, 0, stream>>>(cnt, rowstart, bsum);
    k_scan2<<<1, 512, 0, stream>>>(bsum);
    k_scan3<<<NBLK, 256, 0, stream>>>(rowstart, bsum);
    hipMemsetAsync(cnt, 0, (size_t)NN * 4, stream);  // reuse as scatter cursor
    k_scatter<<<(NE + 255) / 256, 256, 0, stream>>>(edges, mode, dinv, rowstart, cnt, esrc, enorm);
    k_gemm1<<<(NN / 4 * 64) / 256, 256, 0, stream>>>(x, W1, h1p);
    k_gather1<<<(size_t)NN * 64 / 256, 256, 0, stream>>>(rowstart, esrc, enorm, h1p, dinv, b1, h1);
    k_gemm2<<<(NN / 4 * 64) / 256, 256, 0, stream>>>(h1, W2, h2p);
    k_gather2<<<(size_t)NN * 64 / 256, 256, 0, stream>>>(rowstart, esrc, enorm, h2p, dinv, b2, out);
}

// Round 3
// 364.335 us; speedup vs baseline: 1.8171x; 1.1922x over previous
//
#include <hip/hip_runtime.h>
#include <math.h>

#define NN 100000
#define NE 1600000
#define FI 128
#define FH 64
#define FO 16
#define NBLK ((NN + 255) / 256)  // 391

// ---- edge dtype detection: int64 (reference) vs int32 ----
__global__ void k_detect(const int* __restrict__ edges, int* __restrict__ mode) {
    if (blockIdx.x == 0 && threadIdx.x == 0) {
        unsigned orv = 0;
        for (int i = 0; i < 16; ++i) orv |= (unsigned)edges[2 * i + 1];
        *mode = (orv == 0u) ? 1 : 0;  // 1 = int64
    }
}

__device__ __forceinline__ void load_edge(const int* edges, int mode, int e, int& s, int& d) {
    if (mode) { s = edges[2 * e]; d = edges[2 * (NE + e)]; }
    else      { s = edges[e];     d = edges[NE + e]; }
}

// ---- degree count ----
__global__ void k_deg(const int* __restrict__ edges, const int* __restrict__ mode,
                      unsigned* __restrict__ cnt) {
    int e = blockIdx.x * blockDim.x + threadIdx.x;
    if (e >= NE) return;
    int s, d;
    load_edge(edges, *mode, e, s, d);
    atomicAdd(&cnt[d], 1u);
}

__global__ void k_dinv(const unsigned* __restrict__ cnt, float* __restrict__ dinv) {
    int v = blockIdx.x * blockDim.x + threadIdx.x;
    if (v < NN) dinv[v] = rsqrtf((float)(1u + cnt[v]));  // +1 self loop
}

// ---- exclusive scan of cnt -> rowstart (3 kernels) ----
__global__ void k_scan1(const unsigned* __restrict__ cnt, unsigned* __restrict__ rowstart,
                        unsigned* __restrict__ bsum) {
    __shared__ unsigned tmp[256];
    int v = blockIdx.x * 256 + threadIdx.x;
    unsigned x = (v < NN) ? cnt[v] : 0u;
    tmp[threadIdx.x] = x;
    __syncthreads();
    for (int ofs = 1; ofs < 256; ofs <<= 1) {
        unsigned t = (threadIdx.x >= (unsigned)ofs) ? tmp[threadIdx.x - ofs] : 0u;
        __syncthreads();
        tmp[threadIdx.x] += t;
        __syncthreads();
    }
    if (v < NN) rowstart[v] = tmp[threadIdx.x] - x;  // exclusive within block
    if (threadIdx.x == 255) bsum[blockIdx.x] = tmp[255];
}

__global__ void k_scan2(unsigned* __restrict__ bsum) {
    __shared__ unsigned tmp[512];
    int t = threadIdx.x;
    unsigned x = (t < NBLK) ? bsum[t] : 0u;
    tmp[t] = x;
    __syncthreads();
    for (int ofs = 1; ofs < 512; ofs <<= 1) {
        unsigned v = (t >= ofs) ? tmp[t - ofs] : 0u;
        __syncthreads();
        tmp[t] += v;
        __syncthreads();
    }
    if (t < NBLK) bsum[t] = tmp[t] - x;  // exclusive block offsets
}

__global__ void k_scan3(unsigned* __restrict__ rowstart, const unsigned* __restrict__ bsum) {
    int v = blockIdx.x * 256 + threadIdx.x;
    if (v < NN) rowstart[v] += bsum[blockIdx.x];
    if (v == 0) rowstart[NN] = NE;
}

// ---- counting-sort scatter: bucket edges by dst, precompute norm ----
__global__ void k_scatter(const int* __restrict__ edges, const int* __restrict__ mode,
                          const float* __restrict__ dinv, const unsigned* __restrict__ rowstart,
                          unsigned* __restrict__ cur, int* __restrict__ esrc,
                          float* __restrict__ enorm) {
    int e = blockIdx.x * blockDim.x + threadIdx.x;
    if (e >= NE) return;
    int s, d;
    load_edge(edges, *mode, e, s, d);
    unsigned pos = rowstart[d] + atomicAdd(&cur[d], 1u);
    esrc[pos] = s;
    enorm[pos] = dinv[s] * dinv[d];
}

// ---- GEMM1 v2: LDS-tiled, BM=64 BN=64, 4x4 per thread, BK=64 x 2 stages ----
__global__ __launch_bounds__(256) void k_gemm1(const float* __restrict__ x,
                                               const float* __restrict__ W,
                                               float* __restrict__ h) {
    __shared__ float Ws[FI][FH];   // 32 KB, staged once
    __shared__ float As[64][64];   // 16 KB, transposed x-tile As[k][node], 2 stages

    const int tid = threadIdx.x;
    const int tm = tid & 15;       // node-tile slot (x4)
    const int tn = tid >> 4;       // col-tile slot (x4), 0..15
    const int bm = blockIdx.x;
    const int node0 = bm * 64;

    // stage W fully: 128x64 = 2048 float4 / 256 threads = 8 each, coalesced
#pragma unroll
    for (int p = 0; p < 8; ++p) {
        int q = tid + p * 256;          // float4 index
        int row = q >> 4, col4 = (q & 15) * 4;
        *(float4*)&Ws[row][col4] = *(const float4*)&W[row * FH + col4];
    }

    float acc[4][4];
#pragma unroll
    for (int i = 0; i < 4; ++i)
#pragma unroll
        for (int j = 0; j < 4; ++j) acc[i][j] = 0.f;

    const int snode = tid & 63;     // staging: node within tile
    const int wq = tid >> 6;        // staging: wave index 0..3

    for (int s = 0; s < 2; ++s) {
        __syncthreads();  // protect As from previous-stage readers
        // stage As[k][node] for k = s*64 .. s*64+63 (transpose write, conflict-free)
#pragma unroll
        for (int p = 0; p < 4; ++p) {
            int kk = wq * 4 + p * 16;   // local k, 0..60 step 4
            float4 f4 = make_float4(0.f, 0.f, 0.f, 0.f);
            if (node0 + snode < NN)
                f4 = *(const float4*)&x[(size_t)(node0 + snode) * FI + s * 64 + kk];
            As[kk + 0][snode] = f4.x;
            As[kk + 1][snode] = f4.y;
            As[kk + 2][snode] = f4.z;
            As[kk + 3][snode] = f4.w;
        }
        __syncthreads();
#pragma unroll 8
        for (int kl = 0; kl < 64; ++kl) {
            float4 a4 = *(const float4*)&As[kl][tm * 4];
            float4 b4 = *(const float4*)&Ws[s * 64 + kl][tn * 4];
#pragma unroll
            for (int i = 0; i < 4; ++i)
#pragma unroll
                for (int j = 0; j < 4; ++j) acc[i][j] += (&a4.x)[i] * (&b4.x)[j];
        }
    }

#pragma unroll
    for (int i = 0; i < 4; ++i) {
        int node = node0 + tm * 4 + i;
        if (node < NN)
            *(float4*)&h[(size_t)node * FH + tn * 4] =
                make_float4(acc[i][0], acc[i][1], acc[i][2], acc[i][3]);
    }
}

// ---- layer1 aggregate (pull/CSR) + bias + self-loop + relu, fused ----
__global__ __launch_bounds__(256) void k_gather1(const unsigned* __restrict__ rowstart,
                                                 const int* __restrict__ esrc,
                                                 const float* __restrict__ enorm,
                                                 const float* __restrict__ h1p,
                                                 const float* __restrict__ dinv,
                                                 const float* __restrict__ b,
                                                 float* __restrict__ h1out) {
    int v = (blockIdx.x * 256 + threadIdx.x) >> 6;
    int lane = threadIdx.x & 63;
    if (v >= NN) return;
    unsigned beg = rowstart[v], end = rowstart[v + 1];
    float acc = 0.f;
    unsigned i = beg;
    for (; i + 1 < end; i += 2) {
        int s0 = esrc[i], s1 = esrc[i + 1];
        float n0 = enorm[i], n1 = enorm[i + 1];
        float a0 = h1p[s0 * FH + lane];
        float a1 = h1p[s1 * FH + lane];
        acc += a0 * n0 + a1 * n1;
    }
    if (i < end) acc += h1p[esrc[i] * FH + lane] * enorm[i];
    float di = dinv[v];
    float val = acc + h1p[v * FH + lane] * di * di + b[lane];
    h1out[v * FH + lane] = fmaxf(val, 0.f);
}

// ---- GEMM2: [NN,64] @ [64,16] ----
__global__ __launch_bounds__(256) void k_gemm2(const float* __restrict__ h1,
                                               const float* __restrict__ W,
                                               float* __restrict__ h2) {
    __shared__ float Wl[FH * FO];
    for (int i = threadIdx.x; i < FH * FO / 4; i += 256) ((float4*)Wl)[i] = ((const float4*)W)[i];
    __syncthreads();
    int wave = (blockIdx.x * 256 + threadIdx.x) >> 6;
    int sub = (threadIdx.x & 63) >> 4;
    int j = threadIdx.x & 15;
    int node = wave * 4 + sub;
    if (node >= NN) return;
    float acc = 0.f;
    for (int k4 = 0; k4 < FH / 4; ++k4) {
        float4 hv = *(const float4*)&h1[node * FH + k4 * 4];
#pragma unroll
        for (int kk = 0; kk < 4; ++kk) acc += (&hv.x)[kk] * Wl[(k4 * 4 + kk) * FO + j];
    }
    h2[node * FO + j] = acc;
}

// ---- layer2 aggregate (pull/CSR) + bias + self-loop + log_softmax, fused ----
__global__ __launch_bounds__(256) void k_gather2(const unsigned* __restrict__ rowstart,
                                                 const int* __restrict__ esrc,
                                                 const float* __restrict__ enorm,
                                                 const float* __restrict__ h2p,
                                                 const float* __restrict__ dinv,
                                                 const float* __restrict__ b,
                                                 float* __restrict__ out) {
    int v = (blockIdx.x * 256 + threadIdx.x) >> 6;
    int lane = threadIdx.x & 63;
    int g = lane >> 4, j = lane & 15;
    if (v >= NN) return;
    unsigned beg = rowstart[v], end = rowstart[v + 1];
    float acc = 0.f;
    for (unsigned i = beg + g; i < end; i += 4) {
        acc += h2p[esrc[i] * FO + j] * enorm[i];
    }
    acc += __shfl_xor(acc, 16);
    acc += __shfl_xor(acc, 32);
    float di = dinv[v];
    float val = acc + h2p[v * FO + j] * di * di + b[j];
    float m = val;
#pragma unroll
    for (int w = 1; w < 16; w <<= 1) m = fmaxf(m, __shfl_xor(m, w));
    float ex = expf(val - m);
    float ssum = ex;
#pragma unroll
    for (int w = 1; w < 16; w <<= 1) ssum += __shfl_xor(ssum, w);
    float res = val - (m + logf(ssum));
    if (g == 0) out[v * FO + j] = res;
}

extern "C" void kernel_launch(void* const* d_in, const int* in_sizes, int n_in,
                              void* d_out, int out_size, void* d_ws, size_t ws_size,
                              hipStream_t stream) {
    const float* x = (const float*)d_in[0];
    const int* edges = (const int*)d_in[1];
    const float* W1 = (const float*)d_in[2];
    const float* b1 = (const float*)d_in[3];
    const float* W2 = (const float*)d_in[4];
    const float* b2 = (const float*)d_in[5];
    float* out = (float*)d_out;

    char* ws = (char*)d_ws;
    size_t off = 0;
    auto take = [&](size_t bytes) {
        void* p = ws + off;
        off += (bytes + 255) & ~(size_t)255;
        return p;
    };
    int* mode = (int*)take(256);
    unsigned* cnt = (unsigned*)take((size_t)NN * 4);       // degree, then reused as cursor
    float* dinv = (float*)take((size_t)NN * 4);
    unsigned* rowstart = (unsigned*)take((size_t)(NN + 1) * 4);
    unsigned* bsum = (unsigned*)take((size_t)NBLK * 4);
    int* esrc = (int*)take((size_t)NE * 4);
    float* enorm = (float*)take((size_t)NE * 4);
    float* h1p = (float*)take((size_t)NN * FH * 4);
    float* h1 = (float*)take((size_t)NN * FH * 4);
    float* h2p = (float*)take((size_t)NN * FO * 4);

    hipMemsetAsync(cnt, 0, (size_t)NN * 4, stream);
    k_detect<<<1, 64, 0, stream>>>(edges, mode);
    k_deg<<<(NE + 255) / 256, 256, 0, stream>>>(edges, mode, cnt);
    k_dinv<<<(NN + 255) / 256, 256, 0, stream>>>(cnt, dinv);
    k_scan1<<<NBLK, 256, 0, stream>>>(cnt, rowstart, bsum);
    k_scan2<<<1, 512, 0, stream>>>(bsum);
    k_scan3<<<NBLK, 256, 0, stream>>>(rowstart, bsum);
    hipMemsetAsync(cnt, 0, (size_t)NN * 4, stream);  // reuse as scatter cursor
    k_scatter<<<(NE + 255) / 256, 256, 0, stream>>>(edges, mode, dinv, rowstart, cnt, esrc, enorm);
    k_gemm1<<<(NN + 63) / 64, 256, 0, stream>>>(x, W1, h1p);
    k_gather1<<<(size_t)NN * 64 / 256, 256, 0, stream>>>(rowstart, esrc, enorm, h1p, dinv, b1, h1);
    k_gemm2<<<(NN / 4 * 64) / 256, 256, 0, stream>>>(h1, W2, h2p);
    k_gather2<<<(size_t)NN * 64 / 256, 256, 0, stream>>>(rowstart, esrc, enorm, h2p, dinv, b2, out);
}

// Round 4
// 320.723 us; speedup vs baseline: 2.0642x; 1.1360x over previous
//
#include <hip/hip_runtime.h>
#include <math.h>

#define NN 100000
#define NE 1600000
#define FI 128
#define FH 64
#define FO 16
#define NBLK ((NN + 255) / 256)  // 391

struct __align__(8) EP { int s; float n; };

// ---- edge dtype detection: int64 (reference) vs int32 ----
__global__ void k_detect(const int* __restrict__ edges, int* __restrict__ mode) {
    if (blockIdx.x == 0 && threadIdx.x == 0) {
        unsigned orv = 0;
        for (int i = 0; i < 16; ++i) orv |= (unsigned)edges[2 * i + 1];
        *mode = (orv == 0u) ? 1 : 0;  // 1 = int64
    }
}

__device__ __forceinline__ void load_edge(const int* edges, int mode, int e, int& s, int& d) {
    if (mode) { s = edges[2 * e]; d = edges[2 * (NE + e)]; }
    else      { s = edges[e];     d = edges[NE + e]; }
}

// ---- degree count ----
__global__ void k_deg(const int* __restrict__ edges, const int* __restrict__ mode,
                      unsigned* __restrict__ cnt) {
    int e = blockIdx.x * blockDim.x + threadIdx.x;
    if (e >= NE) return;
    int s, d;
    load_edge(edges, *mode, e, s, d);
    atomicAdd(&cnt[d], 1u);
}

__global__ void k_dinv(const unsigned* __restrict__ cnt, float* __restrict__ dinv) {
    int v = blockIdx.x * blockDim.x + threadIdx.x;
    if (v < NN) dinv[v] = rsqrtf((float)(1u + cnt[v]));  // +1 self loop
}

// ---- exclusive scan of cnt -> rowstart (3 kernels) ----
__global__ void k_scan1(const unsigned* __restrict__ cnt, unsigned* __restrict__ rowstart,
                        unsigned* __restrict__ bsum) {
    __shared__ unsigned tmp[256];
    int v = blockIdx.x * 256 + threadIdx.x;
    unsigned x = (v < NN) ? cnt[v] : 0u;
    tmp[threadIdx.x] = x;
    __syncthreads();
    for (int ofs = 1; ofs < 256; ofs <<= 1) {
        unsigned t = (threadIdx.x >= (unsigned)ofs) ? tmp[threadIdx.x - ofs] : 0u;
        __syncthreads();
        tmp[threadIdx.x] += t;
        __syncthreads();
    }
    if (v < NN) rowstart[v] = tmp[threadIdx.x] - x;  // exclusive within block
    if (threadIdx.x == 255) bsum[blockIdx.x] = tmp[255];
}

__global__ void k_scan2(unsigned* __restrict__ bsum) {
    __shared__ unsigned tmp[512];
    int t = threadIdx.x;
    unsigned x = (t < NBLK) ? bsum[t] : 0u;
    tmp[t] = x;
    __syncthreads();
    for (int ofs = 1; ofs < 512; ofs <<= 1) {
        unsigned v = (t >= ofs) ? tmp[t - ofs] : 0u;
        __syncthreads();
        tmp[t] += v;
        __syncthreads();
    }
    if (t < NBLK) bsum[t] = tmp[t] - x;  // exclusive block offsets
}

__global__ void k_scan3(unsigned* __restrict__ rowstart, const unsigned* __restrict__ bsum) {
    int v = blockIdx.x * 256 + threadIdx.x;
    if (v < NN) rowstart[v] += bsum[blockIdx.x];
    if (v == 0) rowstart[NN] = NE;
}

// ---- counting-sort scatter: bucket edges by dst, single 8B payload per edge ----
__global__ void k_scatter(const int* __restrict__ edges, const int* __restrict__ mode,
                          const float* __restrict__ dinv, const unsigned* __restrict__ rowstart,
                          unsigned* __restrict__ cur, EP* __restrict__ ep) {
    int e = blockIdx.x * blockDim.x + threadIdx.x;
    if (e >= NE) return;
    int s, d;
    load_edge(edges, *mode, e, s, d);
    unsigned pos = rowstart[d] + atomicAdd(&cur[d], 1u);
    EP p;
    p.s = s;
    p.n = dinv[s] * dinv[d];
    ep[pos] = p;
}

// ---- GEMM1: LDS-tiled, BM=64 BN=64, 4x4 per thread, BK=64 x 2 stages ----
__global__ __launch_bounds__(256) void k_gemm1(const float* __restrict__ x,
                                               const float* __restrict__ W,
                                               float* __restrict__ h) {
    __shared__ float Ws[FI][FH];
    __shared__ float As[64][64];

    const int tid = threadIdx.x;
    const int tm = tid & 15;
    const int tn = tid >> 4;
    const int node0 = blockIdx.x * 64;

#pragma unroll
    for (int p = 0; p < 8; ++p) {
        int q = tid + p * 256;
        int row = q >> 4, col4 = (q & 15) * 4;
        *(float4*)&Ws[row][col4] = *(const float4*)&W[row * FH + col4];
    }

    float acc[4][4];
#pragma unroll
    for (int i = 0; i < 4; ++i)
#pragma unroll
        for (int j = 0; j < 4; ++j) acc[i][j] = 0.f;

    const int snode = tid & 63;
    const int wq = tid >> 6;

    for (int s = 0; s < 2; ++s) {
        __syncthreads();
#pragma unroll
        for (int p = 0; p < 4; ++p) {
            int kk = wq * 4 + p * 16;
            float4 f4 = make_float4(0.f, 0.f, 0.f, 0.f);
            if (node0 + snode < NN)
                f4 = *(const float4*)&x[(size_t)(node0 + snode) * FI + s * 64 + kk];
            As[kk + 0][snode] = f4.x;
            As[kk + 1][snode] = f4.y;
            As[kk + 2][snode] = f4.z;
            As[kk + 3][snode] = f4.w;
        }
        __syncthreads();
#pragma unroll 8
        for (int kl = 0; kl < 64; ++kl) {
            float4 a4 = *(const float4*)&As[kl][tm * 4];
            float4 b4 = *(const float4*)&Ws[s * 64 + kl][tn * 4];
#pragma unroll
            for (int i = 0; i < 4; ++i)
#pragma unroll
                for (int j = 0; j < 4; ++j) acc[i][j] += (&a4.x)[i] * (&b4.x)[j];
        }
    }

#pragma unroll
    for (int i = 0; i < 4; ++i) {
        int node = node0 + tm * 4 + i;
        if (node < NN)
            *(float4*)&h[(size_t)node * FH + tn * 4] =
                make_float4(acc[i][0], acc[i][1], acc[i][2], acc[i][3]);
    }
}

// ---- layer1 aggregate: wave/node, 2 edge-slots x 32 lanes x float2, unroll 2 ----
__global__ __launch_bounds__(256) void k_gather1(const unsigned* __restrict__ rowstart,
                                                 const EP* __restrict__ ep,
                                                 const float* __restrict__ h1p,
                                                 const float* __restrict__ dinv,
                                                 const float* __restrict__ b,
                                                 float* __restrict__ h1out) {
    int v = (blockIdx.x * 256 + threadIdx.x) >> 6;
    int lane = threadIdx.x & 63;
    int g = lane >> 5;       // edge slot 0/1
    int j = lane & 31;       // float2 feature index
    if (v >= NN) return;
    const float2* h2v = (const float2*)h1p;
    unsigned beg = rowstart[v], end = rowstart[v + 1];
    float ax = 0.f, ay = 0.f;
    unsigned i = beg + g;
    for (; i + 2 < end; i += 4) {
        EP p0 = ep[i];
        EP p1 = ep[i + 2];
        float2 a0 = h2v[(size_t)p0.s * 32 + j];
        float2 a1 = h2v[(size_t)p1.s * 32 + j];
        ax += a0.x * p0.n + a1.x * p1.n;
        ay += a0.y * p0.n + a1.y * p1.n;
    }
    for (; i < end; i += 2) {
        EP p = ep[i];
        float2 a = h2v[(size_t)p.s * 32 + j];
        ax += a.x * p.n;
        ay += a.y * p.n;
    }
    ax += __shfl_xor(ax, 32);
    ay += __shfl_xor(ay, 32);
    if (g == 0) {
        float di = dinv[v];
        float di2 = di * di;
        float2 self = h2v[(size_t)v * 32 + j];
        float2 bb = ((const float2*)b)[j];
        float2 r;
        r.x = fmaxf(ax + self.x * di2 + bb.x, 0.f);
        r.y = fmaxf(ay + self.y * di2 + bb.y, 0.f);
        ((float2*)h1out)[(size_t)v * 32 + j] = r;
    }
}

// ---- GEMM2: [NN,64] @ [64,16] ----
__global__ __launch_bounds__(256) void k_gemm2(const float* __restrict__ h1,
                                               const float* __restrict__ W,
                                               float* __restrict__ h2) {
    __shared__ float Wl[FH * FO];
    for (int i = threadIdx.x; i < FH * FO / 4; i += 256) ((float4*)Wl)[i] = ((const float4*)W)[i];
    __syncthreads();
    int wave = (blockIdx.x * 256 + threadIdx.x) >> 6;
    int sub = (threadIdx.x & 63) >> 4;
    int j = threadIdx.x & 15;
    int node = wave * 4 + sub;
    if (node >= NN) return;
    float acc = 0.f;
    for (int k4 = 0; k4 < FH / 4; ++k4) {
        float4 hv = *(const float4*)&h1[node * FH + k4 * 4];
#pragma unroll
        for (int kk = 0; kk < 4; ++kk) acc += (&hv.x)[kk] * Wl[(k4 * 4 + kk) * FO + j];
    }
    h2[node * FO + j] = acc;
}

// ---- layer2 aggregate + bias + self-loop + log_softmax; 4 edge-slots x 16 lanes, unroll 2 ----
__global__ __launch_bounds__(256) void k_gather2(const unsigned* __restrict__ rowstart,
                                                 const EP* __restrict__ ep,
                                                 const float* __restrict__ h2p,
                                                 const float* __restrict__ dinv,
                                                 const float* __restrict__ b,
                                                 float* __restrict__ out) {
    int v = (blockIdx.x * 256 + threadIdx.x) >> 6;
    int lane = threadIdx.x & 63;
    int g = lane >> 4, j = lane & 15;
    if (v >= NN) return;
    unsigned beg = rowstart[v], end = rowstart[v + 1];
    float acc = 0.f;
    unsigned i = beg + g;
    for (; i + 4 < end; i += 8) {
        EP p0 = ep[i];
        EP p1 = ep[i + 4];
        acc += h2p[(size_t)p0.s * FO + j] * p0.n + h2p[(size_t)p1.s * FO + j] * p1.n;
    }
    for (; i < end; i += 4) {
        EP p = ep[i];
        acc += h2p[(size_t)p.s * FO + j] * p.n;
    }
    acc += __shfl_xor(acc, 16);
    acc += __shfl_xor(acc, 32);
    float di = dinv[v];
    float val = acc + h2p[(size_t)v * FO + j] * di * di + b[j];
    float m = val;
#pragma unroll
    for (int w = 1; w < 16; w <<= 1) m = fmaxf(m, __shfl_xor(m, w));
    float ex = expf(val - m);
    float ssum = ex;
#pragma unroll
    for (int w = 1; w < 16; w <<= 1) ssum += __shfl_xor(ssum, w);
    float res = val - (m + logf(ssum));
    if (g == 0) out[(size_t)v * FO + j] = res;
}

extern "C" void kernel_launch(void* const* d_in, const int* in_sizes, int n_in,
                              void* d_out, int out_size, void* d_ws, size_t ws_size,
                              hipStream_t stream) {
    const float* x = (const float*)d_in[0];
    const int* edges = (const int*)d_in[1];
    const float* W1 = (const float*)d_in[2];
    const float* b1 = (const float*)d_in[3];
    const float* W2 = (const float*)d_in[4];
    const float* b2 = (const float*)d_in[5];
    float* out = (float*)d_out;

    char* ws = (char*)d_ws;
    size_t off = 0;
    auto take = [&](size_t bytes) {
        void* p = ws + off;
        off += (bytes + 255) & ~(size_t)255;
        return p;
    };
    int* mode = (int*)take(256);
    unsigned* cnt = (unsigned*)take((size_t)NN * 4);
    float* dinv = (float*)take((size_t)NN * 4);
    unsigned* rowstart = (unsigned*)take((size_t)(NN + 1) * 4);
    unsigned* bsum = (unsigned*)take((size_t)NBLK * 4);
    EP* ep = (EP*)take((size_t)NE * 8);
    float* h1p = (float*)take((size_t)NN * FH * 4);
    float* h1 = (float*)take((size_t)NN * FH * 4);
    float* h2p = (float*)take((size_t)NN * FO * 4);

    hipMemsetAsync(cnt, 0, (size_t)NN * 4, stream);
    k_detect<<<1, 64, 0, stream>>>(edges, mode);
    k_deg<<<(NE + 255) / 256, 256, 0, stream>>>(edges, mode, cnt);
    k_dinv<<<(NN + 255) / 256, 256, 0, stream>>>(cnt, dinv);
    k_scan1<<<NBLK, 256, 0, stream>>>(cnt, rowstart, bsum);
    k_scan2<<<1, 512, 0, stream>>>(bsum);
    k_scan3<<<NBLK, 256, 0, stream>>>(rowstart, bsum);
    hipMemsetAsync(cnt, 0, (size_t)NN * 4, stream);  // reuse as scatter cursor
    k_scatter<<<(NE + 255) / 256, 256, 0, stream>>>(edges, mode, dinv, rowstart, cnt, ep);
    k_gemm1<<<(NN + 63) / 64, 256, 0, stream>>>(x, W1, h1p);
    k_gather1<<<(size_t)NN * 64 / 256, 256, 0, stream>>>(rowstart, ep, h1p, dinv, b1, h1);
    k_gemm2<<<(NN / 4 * 64) / 256, 256, 0, stream>>>(h1, W2, h2p);
    k_gather2<<<(size_t)NN * 64 / 256, 256, 0, stream>>>(rowstart, ep, h2p, dinv, b2, out);
}

// Round 5
// 316.589 us; speedup vs baseline: 2.0911x; 1.0131x over previous
//
#include <hip/hip_runtime.h>
#include <math.h>

#define NN 100000
#define NE 1600000
#define FI 128
#define FH 64
#define FO 16
#define NBLK ((NN + 255) / 256)   // 391
#define RNG ((NN + 7) / 8)        // 12500 nodes per XCD range
#define EPT 8
#define ECHUNK (256 * EPT)        // 2048 edges per block
#define EBLK ((NE + ECHUNK - 1) / ECHUNK)  // 782

struct __align__(8) EP { int s; float n; };

// ---- edge dtype detection: int64 (reference) vs int32 ----
__global__ void k_detect(const int* __restrict__ edges, int* __restrict__ mode) {
    if (blockIdx.x == 0 && threadIdx.x == 0) {
        unsigned orv = 0;
        for (int i = 0; i < 16; ++i) orv |= (unsigned)edges[2 * i + 1];
        *mode = (orv == 0u) ? 1 : 0;  // 1 = int64
    }
}

__device__ __forceinline__ int load_dst(const int* edges, int mode, int e) {
    return mode ? edges[2 * (NE + e)] : edges[NE + e];
}
__device__ __forceinline__ int load_src(const int* edges, int mode, int e) {
    return mode ? edges[2 * e] : edges[e];
}

// ---- degree count, XCD-partitioned: block b handles dst range (b&7) ----
__global__ void k_deg(const int* __restrict__ edges, const int* __restrict__ mode,
                      unsigned* __restrict__ cnt) {
    const int range = blockIdx.x & 7;
    const int chunk = blockIdx.x >> 3;
    const int lo = range * RNG;
    const int m = *mode;
    int e0 = chunk * ECHUNK + threadIdx.x;
#pragma unroll
    for (int q = 0; q < EPT; ++q) {
        int e = e0 + q * 256;
        if (e >= NE) break;
        int d = load_dst(edges, m, e);
        if ((unsigned)(d - lo) < RNG) atomicAdd(&cnt[d], 1u);
    }
}

__global__ void k_dinv(const unsigned* __restrict__ cnt, float* __restrict__ dinv) {
    int v = blockIdx.x * blockDim.x + threadIdx.x;
    if (v < NN) dinv[v] = rsqrtf((float)(1u + cnt[v]));  // +1 self loop
}

// ---- exclusive scan of cnt -> rowstart (3 kernels) ----
__global__ void k_scan1(const unsigned* __restrict__ cnt, unsigned* __restrict__ rowstart,
                        unsigned* __restrict__ bsum) {
    __shared__ unsigned tmp[256];
    int v = blockIdx.x * 256 + threadIdx.x;
    unsigned x = (v < NN) ? cnt[v] : 0u;
    tmp[threadIdx.x] = x;
    __syncthreads();
    for (int ofs = 1; ofs < 256; ofs <<= 1) {
        unsigned t = (threadIdx.x >= (unsigned)ofs) ? tmp[threadIdx.x - ofs] : 0u;
        __syncthreads();
        tmp[threadIdx.x] += t;
        __syncthreads();
    }
    if (v < NN) rowstart[v] = tmp[threadIdx.x] - x;
    if (threadIdx.x == 255) bsum[blockIdx.x] = tmp[255];
}

__global__ void k_scan2(unsigned* __restrict__ bsum) {
    __shared__ unsigned tmp[512];
    int t = threadIdx.x;
    unsigned x = (t < NBLK) ? bsum[t] : 0u;
    tmp[t] = x;
    __syncthreads();
    for (int ofs = 1; ofs < 512; ofs <<= 1) {
        unsigned v = (t >= ofs) ? tmp[t - ofs] : 0u;
        __syncthreads();
        tmp[t] += v;
        __syncthreads();
    }
    if (t < NBLK) bsum[t] = tmp[t] - x;
}

__global__ void k_scan3(unsigned* __restrict__ rowstart, const unsigned* __restrict__ bsum) {
    int v = blockIdx.x * 256 + threadIdx.x;
    if (v < NN) rowstart[v] += bsum[blockIdx.x];
    if (v == 0) rowstart[NN] = NE;
}

// ---- counting-sort scatter, XCD-partitioned by dst range ----
__global__ void k_scatter(const int* __restrict__ edges, const int* __restrict__ mode,
                          const float* __restrict__ dinv, const unsigned* __restrict__ rowstart,
                          unsigned* __restrict__ cur, EP* __restrict__ ep) {
    const int range = blockIdx.x & 7;
    const int chunk = blockIdx.x >> 3;
    const int lo = range * RNG;
    const int m = *mode;
    int e0 = chunk * ECHUNK + threadIdx.x;
#pragma unroll
    for (int q = 0; q < EPT; ++q) {
        int e = e0 + q * 256;
        if (e >= NE) break;
        int d = load_dst(edges, m, e);
        if ((unsigned)(d - lo) < RNG) {
            int s = load_src(edges, m, e);
            unsigned pos = rowstart[d] + atomicAdd(&cur[d], 1u);
            EP p;
            p.s = s;
            p.n = dinv[s] * dinv[d];
            ep[pos] = p;
        }
    }
}

// ---- GEMM1: LDS-tiled, BM=64 BN=64, 4x4 per thread, BK=64 x 2 stages ----
__global__ __launch_bounds__(256) void k_gemm1(const float* __restrict__ x,
                                               const float* __restrict__ W,
                                               float* __restrict__ h) {
    __shared__ float Ws[FI][FH];
    __shared__ float As[64][64];

    const int tid = threadIdx.x;
    const int tm = tid & 15;
    const int tn = tid >> 4;
    const int node0 = blockIdx.x * 64;

#pragma unroll
    for (int p = 0; p < 8; ++p) {
        int q = tid + p * 256;
        int row = q >> 4, col4 = (q & 15) * 4;
        *(float4*)&Ws[row][col4] = *(const float4*)&W[row * FH + col4];
    }

    float acc[4][4];
#pragma unroll
    for (int i = 0; i < 4; ++i)
#pragma unroll
        for (int j = 0; j < 4; ++j) acc[i][j] = 0.f;

    const int snode = tid & 63;
    const int wq = tid >> 6;

    for (int s = 0; s < 2; ++s) {
        __syncthreads();
#pragma unroll
        for (int p = 0; p < 4; ++p) {
            int kk = wq * 4 + p * 16;
            float4 f4 = make_float4(0.f, 0.f, 0.f, 0.f);
            if (node0 + snode < NN)
                f4 = *(const float4*)&x[(size_t)(node0 + snode) * FI + s * 64 + kk];
            As[kk + 0][snode] = f4.x;
            As[kk + 1][snode] = f4.y;
            As[kk + 2][snode] = f4.z;
            As[kk + 3][snode] = f4.w;
        }
        __syncthreads();
#pragma unroll 8
        for (int kl = 0; kl < 64; ++kl) {
            float4 a4 = *(const float4*)&As[kl][tm * 4];
            float4 b4 = *(const float4*)&Ws[s * 64 + kl][tn * 4];
#pragma unroll
            for (int i = 0; i < 4; ++i)
#pragma unroll
                for (int j = 0; j < 4; ++j) acc[i][j] += (&a4.x)[i] * (&b4.x)[j];
        }
    }

#pragma unroll
    for (int i = 0; i < 4; ++i) {
        int node = node0 + tm * 4 + i;
        if (node < NN)
            *(float4*)&h[(size_t)node * FH + tn * 4] =
                make_float4(acc[i][0], acc[i][1], acc[i][2], acc[i][3]);
    }
}

// ---- layer1 aggregate: wave/node, 4 edge-slots x 16 lanes x float4, unroll 2 ----
__global__ __launch_bounds__(256) void k_gather1(const unsigned* __restrict__ rowstart,
                                                 const EP* __restrict__ ep,
                                                 const float* __restrict__ h1p,
                                                 const float* __restrict__ dinv,
                                                 const float* __restrict__ b,
                                                 float* __restrict__ h1out) {
    int v = (blockIdx.x * 256 + threadIdx.x) >> 6;
    int lane = threadIdx.x & 63;
    int g = lane >> 4;       // edge slot 0..3
    int j = lane & 15;       // float4 chunk within row
    if (v >= NN) return;
    const float4* h4 = (const float4*)h1p;
    unsigned beg = rowstart[v], end = rowstart[v + 1];
    float ax = 0.f, ay = 0.f, az = 0.f, aw = 0.f;
    unsigned i = beg + g;
    for (; i + 4 < end; i += 8) {
        EP p0 = ep[i];
        EP p1 = ep[i + 4];
        float4 a0 = h4[(size_t)p0.s * 16 + j];
        float4 a1 = h4[(size_t)p1.s * 16 + j];
        ax += a0.x * p0.n + a1.x * p1.n;
        ay += a0.y * p0.n + a1.y * p1.n;
        az += a0.z * p0.n + a1.z * p1.n;
        aw += a0.w * p0.n + a1.w * p1.n;
    }
    for (; i < end; i += 4) {
        EP p = ep[i];
        float4 a = h4[(size_t)p.s * 16 + j];
        ax += a.x * p.n;
        ay += a.y * p.n;
        az += a.z * p.n;
        aw += a.w * p.n;
    }
#pragma unroll
    for (int w = 16; w < 64; w <<= 1) {
        ax += __shfl_xor(ax, w);
        ay += __shfl_xor(ay, w);
        az += __shfl_xor(az, w);
        aw += __shfl_xor(aw, w);
    }
    if (g == 0) {
        float di = dinv[v];
        float di2 = di * di;
        float4 self = h4[(size_t)v * 16 + j];
        float4 bb = ((const float4*)b)[j];
        float4 r;
        r.x = fmaxf(ax + self.x * di2 + bb.x, 0.f);
        r.y = fmaxf(ay + self.y * di2 + bb.y, 0.f);
        r.z = fmaxf(az + self.z * di2 + bb.z, 0.f);
        r.w = fmaxf(aw + self.w * di2 + bb.w, 0.f);
        ((float4*)h1out)[(size_t)v * 16 + j] = r;
    }
}

// ---- GEMM2: [NN,64] @ [64,16] ----
__global__ __launch_bounds__(256) void k_gemm2(const float* __restrict__ h1,
                                               const float* __restrict__ W,
                                               float* __restrict__ h2) {
    __shared__ float Wl[FH * FO];
    for (int i = threadIdx.x; i < FH * FO / 4; i += 256) ((float4*)Wl)[i] = ((const float4*)W)[i];
    __syncthreads();
    int wave = (blockIdx.x * 256 + threadIdx.x) >> 6;
    int sub = (threadIdx.x & 63) >> 4;
    int j = threadIdx.x & 15;
    int node = wave * 4 + sub;
    if (node >= NN) return;
    float acc = 0.f;
    for (int k4 = 0; k4 < FH / 4; ++k4) {
        float4 hv = *(const float4*)&h1[node * FH + k4 * 4];
#pragma unroll
        for (int kk = 0; kk < 4; ++kk) acc += (&hv.x)[kk] * Wl[(k4 * 4 + kk) * FO + j];
    }
    h2[node * FO + j] = acc;
}

// ---- layer2 aggregate + bias + self-loop + log_softmax; 4 edge-slots x 16 lanes, unroll 2 ----
__global__ __launch_bounds__(256) void k_gather2(const unsigned* __restrict__ rowstart,
                                                 const EP* __restrict__ ep,
                                                 const float* __restrict__ h2p,
                                                 const float* __restrict__ dinv,
                                                 const float* __restrict__ b,
                                                 float* __restrict__ out) {
    int v = (blockIdx.x * 256 + threadIdx.x) >> 6;
    int lane = threadIdx.x & 63;
    int g = lane >> 4, j = lane & 15;
    if (v >= NN) return;
    unsigned beg = rowstart[v], end = rowstart[v + 1];
    float acc = 0.f;
    unsigned i = beg + g;
    for (; i + 4 < end; i += 8) {
        EP p0 = ep[i];
        EP p1 = ep[i + 4];
        acc += h2p[(size_t)p0.s * FO + j] * p0.n + h2p[(size_t)p1.s * FO + j] * p1.n;
    }
    for (; i < end; i += 4) {
        EP p = ep[i];
        acc += h2p[(size_t)p.s * FO + j] * p.n;
    }
    acc += __shfl_xor(acc, 16);
    acc += __shfl_xor(acc, 32);
    float di = dinv[v];
    float val = acc + h2p[(size_t)v * FO + j] * di * di + b[j];
    float m = val;
#pragma unroll
    for (int w = 1; w < 16; w <<= 1) m = fmaxf(m, __shfl_xor(m, w));
    float ex = expf(val - m);
    float ssum = ex;
#pragma unroll
    for (int w = 1; w < 16; w <<= 1) ssum += __shfl_xor(ssum, w);
    float res = val - (m + logf(ssum));
    if (g == 0) out[(size_t)v * FO + j] = res;
}

extern "C" void kernel_launch(void* const* d_in, const int* in_sizes, int n_in,
                              void* d_out, int out_size, void* d_ws, size_t ws_size,
                              hipStream_t stream) {
    const float* x = (const float*)d_in[0];
    const int* edges = (const int*)d_in[1];
    const float* W1 = (const float*)d_in[2];
    const float* b1 = (const float*)d_in[3];
    const float* W2 = (const float*)d_in[4];
    const float* b2 = (const float*)d_in[5];
    float* out = (float*)d_out;

    char* ws = (char*)d_ws;
    size_t off = 0;
    auto take = [&](size_t bytes) {
        void* p = ws + off;
        off += (bytes + 255) & ~(size_t)255;
        return p;
    };
    int* mode = (int*)take(256);
    unsigned* cnt = (unsigned*)take((size_t)NN * 4);
    float* dinv = (float*)take((size_t)NN * 4);
    unsigned* rowstart = (unsigned*)take((size_t)(NN + 1) * 4);
    unsigned* bsum = (unsigned*)take((size_t)NBLK * 4);
    EP* ep = (EP*)take((size_t)NE * 8);
    float* h1p = (float*)take((size_t)NN * FH * 4);
    float* h1 = (float*)take((size_t)NN * FH * 4);
    float* h2p = (float*)take((size_t)NN * FO * 4);

    hipMemsetAsync(cnt, 0, (size_t)NN * 4, stream);
    k_detect<<<1, 64, 0, stream>>>(edges, mode);
    k_deg<<<EBLK * 8, 256, 0, stream>>>(edges, mode, cnt);
    k_dinv<<<(NN + 255) / 256, 256, 0, stream>>>(cnt, dinv);
    k_scan1<<<NBLK, 256, 0, stream>>>(cnt, rowstart, bsum);
    k_scan2<<<1, 512, 0, stream>>>(bsum);
    k_scan3<<<NBLK, 256, 0, stream>>>(rowstart, bsum);
    hipMemsetAsync(cnt, 0, (size_t)NN * 4, stream);  // reuse as scatter cursor
    k_scatter<<<EBLK * 8, 256, 0, stream>>>(edges, mode, dinv, rowstart, cnt, ep);
    k_gemm1<<<(NN + 63) / 64, 256, 0, stream>>>(x, W1, h1p);
    k_gather1<<<(size_t)NN * 64 / 256, 256, 0, stream>>>(rowstart, ep, h1p, dinv, b1, h1);
    k_gemm2<<<(NN / 4 * 64) / 256, 256, 0, stream>>>(h1, W2, h2p);
    k_gather2<<<(size_t)NN * 64 / 256, 256, 0, stream>>>(rowstart, ep, h2p, dinv, b2, out);
}

// Round 6
// 216.987 us; speedup vs baseline: 3.0510x; 1.4590x over previous
//
#include <hip/hip_runtime.h>
#include <math.h>

#define NN 100000
#define NE 1600000
#define FI 128
#define FH 64
#define FO 16
#define NB 392            // buckets of 256 nodes (392*256 = 100352 >= NN)
#define BCAP 5632         // max edges/bucket (mean 4082, sigma ~64 -> 24 sigma)
#define AEPT 32
#define ACHUNK (256 * AEPT)                 // 8192 edges per phase-A block
#define ABLK ((NE + ACHUNK - 1) / ACHUNK)   // 196

// ---- edge dtype detection: int64 (reference) vs int32 ----
__global__ void k_detect(const int* __restrict__ edges, int* __restrict__ mode) {
    if (blockIdx.x == 0 && threadIdx.x == 0) {
        unsigned orv = 0;
        for (int i = 0; i < 16; ++i) orv |= (unsigned)edges[2 * i + 1];
        *mode = (orv == 0u) ? 1 : 0;  // 1 = int64
    }
}

__device__ __forceinline__ int load_dst(const int* edges, int mode, int e) {
    return mode ? edges[2 * (NE + e)] : edges[NE + e];
}
__device__ __forceinline__ int load_src(const int* edges, int mode, int e) {
    return mode ? edges[2 * e] : edges[e];
}

// ---- phase A: partition edges into 392 dst-buckets, 4B packed payload ----
__global__ __launch_bounds__(256) void k_phaseA(const int* __restrict__ edges,
                                                const int* __restrict__ mode,
                                                unsigned* __restrict__ bcur,
                                                unsigned* __restrict__ staged) {
    __shared__ unsigned hcnt[NB];
    __shared__ unsigned hrun[NB];
    __shared__ unsigned hcur[NB];
    const int m = *mode;
    for (int i = threadIdx.x; i < NB; i += 256) { hcnt[i] = 0; hcur[i] = 0; }
    __syncthreads();
    const int e0 = blockIdx.x * ACHUNK + threadIdx.x;
#pragma unroll
    for (int q = 0; q < AEPT; ++q) {
        int e = e0 + q * 256;
        if (e < NE) atomicAdd(&hcnt[load_dst(edges, m, e) >> 8], 1u);
    }
    __syncthreads();
    for (int i = threadIdx.x; i < NB; i += 256)
        hrun[i] = atomicAdd(&bcur[i], hcnt[i]);  // reserve contiguous run per bucket
    __syncthreads();
#pragma unroll
    for (int q = 0; q < AEPT; ++q) {
        int e = e0 + q * 256;
        if (e < NE) {
            int d = load_dst(edges, m, e);
            int s = load_src(edges, m, e);
            int b = d >> 8;
            unsigned r = hrun[b] + atomicAdd(&hcur[b], 1u);
            if (r < BCAP)
                staged[(size_t)b * BCAP + r] = ((unsigned)s << 8) | (unsigned)(d & 255);
        }
    }
}

// ---- tiny scan: bucket counts -> exclusive bucket bases ----
__global__ void k_bscan(const unsigned* __restrict__ bcur, unsigned* __restrict__ bbase) {
    __shared__ unsigned tmp[512];
    int t = threadIdx.x;
    unsigned x = (t < NB) ? bcur[t] : 0u;
    tmp[t] = x;
    __syncthreads();
    for (int ofs = 1; ofs < 512; ofs <<= 1) {
        unsigned v = (t >= ofs) ? tmp[t - ofs] : 0u;
        __syncthreads();
        tmp[t] += v;
        __syncthreads();
    }
    if (t < NB) bbase[t] = tmp[t] - x;
}

// ---- phase B: per-bucket counting sort; writes rowstart + src-only CSR ----
__global__ __launch_bounds__(256) void k_phaseB(const unsigned* __restrict__ staged,
                                                const unsigned* __restrict__ bcur,
                                                const unsigned* __restrict__ bbase,
                                                unsigned* __restrict__ rowstart,
                                                int* __restrict__ esrc) {
    __shared__ unsigned hist[256], hb[256], hcur[256], tmp[256];
    const int b = blockIdx.x;
    const int t = threadIdx.x;
    const unsigned cnt = min(bcur[b], (unsigned)BCAP);
    const unsigned base = bbase[b];
    hist[t] = 0;
    hcur[t] = 0;
    __syncthreads();
    const unsigned* sb = staged + (size_t)b * BCAP;
    for (unsigned i = t; i < cnt; i += 256) atomicAdd(&hist[sb[i] & 255u], 1u);
    __syncthreads();
    unsigned x = hist[t];
    tmp[t] = x;
    __syncthreads();
    for (int ofs = 1; ofs < 256; ofs <<= 1) {
        unsigned v = (t >= ofs) ? tmp[t - ofs] : 0u;
        __syncthreads();
        tmp[t] += v;
        __syncthreads();
    }
    hb[t] = tmp[t] - x;  // exclusive scan
    int v = b * 256 + t;
    if (v <= NN) rowstart[v] = base + hb[t];  // v==NN lands in bucket 390 (all buckets >390 empty)
    __syncthreads();
    for (unsigned i = t; i < cnt; i += 256) {
        unsigned p = sb[i];
        unsigned dlo = p & 255u;
        unsigned pos = base + hb[dlo] + atomicAdd(&hcur[dlo], 1u);
        esrc[pos] = (int)(p >> 8);
    }
}

__global__ void k_dinv(const unsigned* __restrict__ rowstart, float* __restrict__ dinv) {
    int v = blockIdx.x * blockDim.x + threadIdx.x;
    if (v < NN) dinv[v] = rsqrtf((float)(1u + rowstart[v + 1] - rowstart[v]));
}

// ---- GEMM1: LDS-tiled, BM=64 BN=64, 4x4 per thread, BK=64 x 2 stages ----
__global__ __launch_bounds__(256) void k_gemm1(const float* __restrict__ x,
                                               const float* __restrict__ W,
                                               float* __restrict__ h) {
    __shared__ float Ws[FI][FH];
    __shared__ float As[64][64];

    const int tid = threadIdx.x;
    const int tm = tid & 15;
    const int tn = tid >> 4;
    const int node0 = blockIdx.x * 64;

#pragma unroll
    for (int p = 0; p < 8; ++p) {
        int q = tid + p * 256;
        int row = q >> 4, col4 = (q & 15) * 4;
        *(float4*)&Ws[row][col4] = *(const float4*)&W[row * FH + col4];
    }

    float acc[4][4];
#pragma unroll
    for (int i = 0; i < 4; ++i)
#pragma unroll
        for (int j = 0; j < 4; ++j) acc[i][j] = 0.f;

    const int snode = tid & 63;
    const int wq = tid >> 6;

    for (int s = 0; s < 2; ++s) {
        __syncthreads();
#pragma unroll
        for (int p = 0; p < 4; ++p) {
            int kk = wq * 4 + p * 16;
            float4 f4 = make_float4(0.f, 0.f, 0.f, 0.f);
            if (node0 + snode < NN)
                f4 = *(const float4*)&x[(size_t)(node0 + snode) * FI + s * 64 + kk];
            As[kk + 0][snode] = f4.x;
            As[kk + 1][snode] = f4.y;
            As[kk + 2][snode] = f4.z;
            As[kk + 3][snode] = f4.w;
        }
        __syncthreads();
#pragma unroll 8
        for (int kl = 0; kl < 64; ++kl) {
            float4 a4 = *(const float4*)&As[kl][tm * 4];
            float4 b4 = *(const float4*)&Ws[s * 64 + kl][tn * 4];
#pragma unroll
            for (int i = 0; i < 4; ++i)
#pragma unroll
                for (int j = 0; j < 4; ++j) acc[i][j] += (&a4.x)[i] * (&b4.x)[j];
        }
    }

#pragma unroll
    for (int i = 0; i < 4; ++i) {
        int node = node0 + tm * 4 + i;
        if (node < NN)
            *(float4*)&h[(size_t)node * FH + tn * 4] =
                make_float4(acc[i][0], acc[i][1], acc[i][2], acc[i][3]);
    }
}

// ---- layer1 aggregate: wave/node, 4 edge-slots x 16 lanes x float4, src-only CSR ----
__global__ __launch_bounds__(256) void k_gather1(const unsigned* __restrict__ rowstart,
                                                 const int* __restrict__ esrc,
                                                 const float* __restrict__ h1p,
                                                 const float* __restrict__ dinv,
                                                 const float* __restrict__ b,
                                                 float* __restrict__ h1out) {
    int v = (blockIdx.x * 256 + threadIdx.x) >> 6;
    int lane = threadIdx.x & 63;
    int g = lane >> 4;
    int j = lane & 15;
    if (v >= NN) return;
    const float4* h4 = (const float4*)h1p;
    unsigned beg = rowstart[v], end = rowstart[v + 1];
    float dv = dinv[v];
    float ax = 0.f, ay = 0.f, az = 0.f, aw = 0.f;
    unsigned i = beg + g;
    for (; i + 4 < end; i += 8) {
        int s0 = esrc[i], s1 = esrc[i + 4];
        float n0 = dinv[s0] * dv, n1 = dinv[s1] * dv;
        float4 a0 = h4[(size_t)s0 * 16 + j];
        float4 a1 = h4[(size_t)s1 * 16 + j];
        ax += a0.x * n0 + a1.x * n1;
        ay += a0.y * n0 + a1.y * n1;
        az += a0.z * n0 + a1.z * n1;
        aw += a0.w * n0 + a1.w * n1;
    }
    for (; i < end; i += 4) {
        int s = esrc[i];
        float n = dinv[s] * dv;
        float4 a = h4[(size_t)s * 16 + j];
        ax += a.x * n;
        ay += a.y * n;
        az += a.z * n;
        aw += a.w * n;
    }
#pragma unroll
    for (int w = 16; w < 64; w <<= 1) {
        ax += __shfl_xor(ax, w);
        ay += __shfl_xor(ay, w);
        az += __shfl_xor(az, w);
        aw += __shfl_xor(aw, w);
    }
    if (g == 0) {
        float di2 = dv * dv;
        float4 self = h4[(size_t)v * 16 + j];
        float4 bb = ((const float4*)b)[j];
        float4 r;
        r.x = fmaxf(ax + self.x * di2 + bb.x, 0.f);
        r.y = fmaxf(ay + self.y * di2 + bb.y, 0.f);
        r.z = fmaxf(az + self.z * di2 + bb.z, 0.f);
        r.w = fmaxf(aw + self.w * di2 + bb.w, 0.f);
        ((float4*)h1out)[(size_t)v * 16 + j] = r;
    }
}

// ---- GEMM2: [NN,64] @ [64,16] ----
__global__ __launch_bounds__(256) void k_gemm2(const float* __restrict__ h1,
                                               const float* __restrict__ W,
                                               float* __restrict__ h2) {
    __shared__ float Wl[FH * FO];
    for (int i = threadIdx.x; i < FH * FO / 4; i += 256) ((float4*)Wl)[i] = ((const float4*)W)[i];
    __syncthreads();
    int wave = (blockIdx.x * 256 + threadIdx.x) >> 6;
    int sub = (threadIdx.x & 63) >> 4;
    int j = threadIdx.x & 15;
    int node = wave * 4 + sub;
    if (node >= NN) return;
    float acc = 0.f;
    for (int k4 = 0; k4 < FH / 4; ++k4) {
        float4 hv = *(const float4*)&h1[node * FH + k4 * 4];
#pragma unroll
        for (int kk = 0; kk < 4; ++kk) acc += (&hv.x)[kk] * Wl[(k4 * 4 + kk) * FO + j];
    }
    h2[node * FO + j] = acc;
}

// ---- layer2 aggregate + bias + self-loop + log_softmax; src-only CSR ----
__global__ __launch_bounds__(256) void k_gather2(const unsigned* __restrict__ rowstart,
                                                 const int* __restrict__ esrc,
                                                 const float* __restrict__ h2p,
                                                 const float* __restrict__ dinv,
                                                 const float* __restrict__ b,
                                                 float* __restrict__ out) {
    int v = (blockIdx.x * 256 + threadIdx.x) >> 6;
    int lane = threadIdx.x & 63;
    int g = lane >> 4, j = lane & 15;
    if (v >= NN) return;
    unsigned beg = rowstart[v], end = rowstart[v + 1];
    float dv = dinv[v];
    float acc = 0.f;
    unsigned i = beg + g;
    for (; i + 4 < end; i += 8) {
        int s0 = esrc[i], s1 = esrc[i + 4];
        float n0 = dinv[s0] * dv, n1 = dinv[s1] * dv;
        acc += h2p[(size_t)s0 * FO + j] * n0 + h2p[(size_t)s1 * FO + j] * n1;
    }
    for (; i < end; i += 4) {
        int s = esrc[i];
        acc += h2p[(size_t)s * FO + j] * (dinv[s] * dv);
    }
    acc += __shfl_xor(acc, 16);
    acc += __shfl_xor(acc, 32);
    float val = acc + h2p[(size_t)v * FO + j] * dv * dv + b[j];
    float m = val;
#pragma unroll
    for (int w = 1; w < 16; w <<= 1) m = fmaxf(m, __shfl_xor(m, w));
    float ex = expf(val - m);
    float ssum = ex;
#pragma unroll
    for (int w = 1; w < 16; w <<= 1) ssum += __shfl_xor(ssum, w);
    float res = val - (m + logf(ssum));
    if (g == 0) out[(size_t)v * FO + j] = res;
}

extern "C" void kernel_launch(void* const* d_in, const int* in_sizes, int n_in,
                              void* d_out, int out_size, void* d_ws, size_t ws_size,
                              hipStream_t stream) {
    const float* x = (const float*)d_in[0];
    const int* edges = (const int*)d_in[1];
    const float* W1 = (const float*)d_in[2];
    const float* b1 = (const float*)d_in[3];
    const float* W2 = (const float*)d_in[4];
    const float* b2 = (const float*)d_in[5];
    float* out = (float*)d_out;

    char* ws = (char*)d_ws;
    size_t off = 0;
    auto take = [&](size_t bytes) {
        void* p = ws + off;
        off += (bytes + 255) & ~(size_t)255;
        return p;
    };
    int* mode = (int*)take(256);
    unsigned* bcur = (unsigned*)take((size_t)NB * 4);
    unsigned* bbase = (unsigned*)take((size_t)NB * 4);
    unsigned* rowstart = (unsigned*)take((size_t)(NN + 1) * 4);
    float* dinv = (float*)take((size_t)NN * 4);
    int* esrc = (int*)take((size_t)NE * 4);
    float* h1p = (float*)take((size_t)NN * FH * 4);
    float* h1 = (float*)take((size_t)NN * FH * 4);
    float* h2p = (float*)take((size_t)NN * FO * 4);
    unsigned* staged = (unsigned*)h1;  // alias: staged (8.8 MB) dead before gather1 writes h1

    hipMemsetAsync(bcur, 0, (size_t)NB * 4, stream);
    k_detect<<<1, 64, 0, stream>>>(edges, mode);
    k_phaseA<<<ABLK, 256, 0, stream>>>(edges, mode, bcur, staged);
    k_bscan<<<1, 512, 0, stream>>>(bcur, bbase);
    k_phaseB<<<NB, 256, 0, stream>>>(staged, bcur, bbase, rowstart, esrc);
    k_dinv<<<(NN + 255) / 256, 256, 0, stream>>>(rowstart, dinv);
    k_gemm1<<<(NN + 63) / 64, 256, 0, stream>>>(x, W1, h1p);
    k_gather1<<<(size_t)NN * 64 / 256, 256, 0, stream>>>(rowstart, esrc, h1p, dinv, b1, h1);
    k_gemm2<<<(NN / 4 * 64) / 256, 256, 0, stream>>>(h1, W2, h2p);
    k_gather2<<<(size_t)NN * 64 / 256, 256, 0, stream>>>(rowstart, esrc, h2p, dinv, b2, out);
}

// Round 7
// 197.440 us; speedup vs baseline: 3.3530x; 1.0990x over previous
//
#include <hip/hip_runtime.h>
#include <math.h>

#define NN 100000
#define NE 1600000
#define FI 128
#define FH 64
#define FO 16
#define NB 392            // buckets of 256 nodes
#define BCAP 5632
#define AEPT 32
#define ACHUNK (256 * AEPT)
#define ABLK ((NE + ACHUNK - 1) / ACHUNK)  // 196

typedef unsigned short ushort_t;

__device__ __forceinline__ ushort_t f2bf(float f) {
    unsigned u = __float_as_uint(f);
    u = (u + 0x7fffu + ((u >> 16) & 1u)) >> 16;  // RNE
    return (ushort_t)u;
}
__device__ __forceinline__ float bf2f(ushort_t h) {
    return __uint_as_float((unsigned)h << 16);
}

// ---- edge dtype detection ----
__global__ void k_detect(const int* __restrict__ edges, int* __restrict__ mode) {
    if (blockIdx.x == 0 && threadIdx.x == 0) {
        unsigned orv = 0;
        for (int i = 0; i < 16; ++i) orv |= (unsigned)edges[2 * i + 1];
        *mode = (orv == 0u) ? 1 : 0;  // 1 = int64
    }
}

__device__ __forceinline__ int load_dst(const int* edges, int mode, int e) {
    return mode ? edges[2 * (NE + e)] : edges[NE + e];
}
__device__ __forceinline__ int load_src(const int* edges, int mode, int e) {
    return mode ? edges[2 * e] : edges[e];
}

// ---- phase A: partition edges into 392 dst-buckets ----
__global__ __launch_bounds__(256) void k_phaseA(const int* __restrict__ edges,
                                                const int* __restrict__ mode,
                                                unsigned* __restrict__ bcur,
                                                unsigned* __restrict__ staged) {
    __shared__ unsigned hcnt[NB];
    __shared__ unsigned hrun[NB];
    __shared__ unsigned hcur[NB];
    const int m = *mode;
    for (int i = threadIdx.x; i < NB; i += 256) { hcnt[i] = 0; hcur[i] = 0; }
    __syncthreads();
    const int e0 = blockIdx.x * ACHUNK + threadIdx.x;
#pragma unroll
    for (int q = 0; q < AEPT; ++q) {
        int e = e0 + q * 256;
        if (e < NE) atomicAdd(&hcnt[load_dst(edges, m, e) >> 8], 1u);
    }
    __syncthreads();
    for (int i = threadIdx.x; i < NB; i += 256)
        hrun[i] = atomicAdd(&bcur[i], hcnt[i]);
    __syncthreads();
#pragma unroll
    for (int q = 0; q < AEPT; ++q) {
        int e = e0 + q * 256;
        if (e < NE) {
            int d = load_dst(edges, m, e);
            int s = load_src(edges, m, e);
            int b = d >> 8;
            unsigned r = hrun[b] + atomicAdd(&hcur[b], 1u);
            if (r < BCAP)
                staged[(size_t)b * BCAP + r] = ((unsigned)s << 8) | (unsigned)(d & 255);
        }
    }
}

__global__ void k_bscan(const unsigned* __restrict__ bcur, unsigned* __restrict__ bbase) {
    __shared__ unsigned tmp[512];
    int t = threadIdx.x;
    unsigned x = (t < NB) ? bcur[t] : 0u;
    tmp[t] = x;
    __syncthreads();
    for (int ofs = 1; ofs < 512; ofs <<= 1) {
        unsigned v = (t >= ofs) ? tmp[t - ofs] : 0u;
        __syncthreads();
        tmp[t] += v;
        __syncthreads();
    }
    if (t < NB) bbase[t] = tmp[t] - x;
}

// ---- phase B: per-bucket counting sort -> rowstart + src-only CSR ----
__global__ __launch_bounds__(256) void k_phaseB(const unsigned* __restrict__ staged,
                                                const unsigned* __restrict__ bcur,
                                                const unsigned* __restrict__ bbase,
                                                unsigned* __restrict__ rowstart,
                                                int* __restrict__ esrc) {
    __shared__ unsigned hist[256], hb[256], hcur[256], tmp[256];
    const int b = blockIdx.x;
    const int t = threadIdx.x;
    const unsigned cnt = min(bcur[b], (unsigned)BCAP);
    const unsigned base = bbase[b];
    hist[t] = 0;
    hcur[t] = 0;
    __syncthreads();
    const unsigned* sb = staged + (size_t)b * BCAP;
    for (unsigned i = t; i < cnt; i += 256) atomicAdd(&hist[sb[i] & 255u], 1u);
    __syncthreads();
    unsigned x = hist[t];
    tmp[t] = x;
    __syncthreads();
    for (int ofs = 1; ofs < 256; ofs <<= 1) {
        unsigned v = (t >= ofs) ? tmp[t - ofs] : 0u;
        __syncthreads();
        tmp[t] += v;
        __syncthreads();
    }
    hb[t] = tmp[t] - x;
    int v = b * 256 + t;
    if (v <= NN) rowstart[v] = base + hb[t];
    __syncthreads();
    for (unsigned i = t; i < cnt; i += 256) {
        unsigned p = sb[i];
        unsigned dlo = p & 255u;
        unsigned pos = base + hb[dlo] + atomicAdd(&hcur[dlo], 1u);
        esrc[pos] = (int)(p >> 8);
    }
}

__global__ void k_dinv(const unsigned* __restrict__ rowstart, float* __restrict__ dinv) {
    int v = blockIdx.x * blockDim.x + threadIdx.x;
    if (v < NN) dinv[v] = rsqrtf((float)(1u + rowstart[v + 1] - rowstart[v]));
}

// ---- GEMM1: LDS-tiled, bf16 output ----
__global__ __launch_bounds__(256) void k_gemm1(const float* __restrict__ x,
                                               const float* __restrict__ W,
                                               ushort_t* __restrict__ h) {
    __shared__ float Ws[FI][FH];
    __shared__ float As[64][64];

    const int tid = threadIdx.x;
    const int tm = tid & 15;
    const int tn = tid >> 4;
    const int node0 = blockIdx.x * 64;

#pragma unroll
    for (int p = 0; p < 8; ++p) {
        int q = tid + p * 256;
        int row = q >> 4, col4 = (q & 15) * 4;
        *(float4*)&Ws[row][col4] = *(const float4*)&W[row * FH + col4];
    }

    float acc[4][4];
#pragma unroll
    for (int i = 0; i < 4; ++i)
#pragma unroll
        for (int j = 0; j < 4; ++j) acc[i][j] = 0.f;

    const int snode = tid & 63;
    const int wq = tid >> 6;

    for (int s = 0; s < 2; ++s) {
        __syncthreads();
#pragma unroll
        for (int p = 0; p < 4; ++p) {
            int kk = wq * 4 + p * 16;
            float4 f4 = make_float4(0.f, 0.f, 0.f, 0.f);
            if (node0 + snode < NN)
                f4 = *(const float4*)&x[(size_t)(node0 + snode) * FI + s * 64 + kk];
            As[kk + 0][snode] = f4.x;
            As[kk + 1][snode] = f4.y;
            As[kk + 2][snode] = f4.z;
            As[kk + 3][snode] = f4.w;
        }
        __syncthreads();
#pragma unroll 8
        for (int kl = 0; kl < 64; ++kl) {
            float4 a4 = *(const float4*)&As[kl][tm * 4];
            float4 b4 = *(const float4*)&Ws[s * 64 + kl][tn * 4];
#pragma unroll
            for (int i = 0; i < 4; ++i)
#pragma unroll
                for (int j = 0; j < 4; ++j) acc[i][j] += (&a4.x)[i] * (&b4.x)[j];
        }
    }

#pragma unroll
    for (int i = 0; i < 4; ++i) {
        int node = node0 + tm * 4 + i;
        if (node < NN) {
            ushort4 r;
            r.x = f2bf(acc[i][0]);
            r.y = f2bf(acc[i][1]);
            r.z = f2bf(acc[i][2]);
            r.w = f2bf(acc[i][3]);
            *(ushort4*)&h[(size_t)node * FH + tn * 4] = r;
        }
    }
}

// ---- layer1 aggregate: 8 edge-slots x 8 lanes x 16B(bf16x8), unroll 2 ----
__global__ __launch_bounds__(256) void k_gather1(const unsigned* __restrict__ rowstart,
                                                 const int* __restrict__ esrc,
                                                 const ushort_t* __restrict__ h1p,
                                                 const float* __restrict__ dinv,
                                                 const float* __restrict__ b,
                                                 float* __restrict__ h1out) {
    int v = (blockIdx.x * 256 + threadIdx.x) >> 6;
    int lane = threadIdx.x & 63;
    int g = lane >> 3;       // edge slot 0..7
    int j = lane & 7;        // 16B chunk within 128B row
    if (v >= NN) return;
    const uint4* h4 = (const uint4*)h1p;   // row = 8 uint4
    unsigned beg = rowstart[v], end = rowstart[v + 1];
    float dv = dinv[v];
    float a0 = 0.f, a1 = 0.f, a2 = 0.f, a3 = 0.f, a4 = 0.f, a5 = 0.f, a6 = 0.f, a7 = 0.f;
#define ACCUM(u4, n)                                             \
    {                                                            \
        a0 += bf2f((ushort_t)(u4.x & 0xffffu)) * n;              \
        a1 += bf2f((ushort_t)(u4.x >> 16)) * n;                  \
        a2 += bf2f((ushort_t)(u4.y & 0xffffu)) * n;              \
        a3 += bf2f((ushort_t)(u4.y >> 16)) * n;                  \
        a4 += bf2f((ushort_t)(u4.z & 0xffffu)) * n;              \
        a5 += bf2f((ushort_t)(u4.z >> 16)) * n;                  \
        a6 += bf2f((ushort_t)(u4.w & 0xffffu)) * n;              \
        a7 += bf2f((ushort_t)(u4.w >> 16)) * n;                  \
    }
    unsigned i = beg + g;
    for (; i + 8 < end; i += 16) {
        int s0 = esrc[i], s1 = esrc[i + 8];
        float n0 = dinv[s0] * dv, n1 = dinv[s1] * dv;
        uint4 u0 = h4[(size_t)s0 * 8 + j];
        uint4 u1 = h4[(size_t)s1 * 8 + j];
        ACCUM(u0, n0);
        ACCUM(u1, n1);
    }
    for (; i < end; i += 8) {
        int s = esrc[i];
        float n = dinv[s] * dv;
        uint4 u = h4[(size_t)s * 8 + j];
        ACCUM(u, n);
    }
#pragma unroll
    for (int w = 8; w < 64; w <<= 1) {
        a0 += __shfl_xor(a0, w);
        a1 += __shfl_xor(a1, w);
        a2 += __shfl_xor(a2, w);
        a3 += __shfl_xor(a3, w);
        a4 += __shfl_xor(a4, w);
        a5 += __shfl_xor(a5, w);
        a6 += __shfl_xor(a6, w);
        a7 += __shfl_xor(a7, w);
    }
    if (g == 0) {
        float di2 = dv * dv;
        uint4 us = h4[(size_t)v * 8 + j];
        float4 b0 = ((const float4*)b)[j * 2];
        float4 b1 = ((const float4*)b)[j * 2 + 1];
        float4 r0, r1;
        r0.x = fmaxf(a0 + bf2f((ushort_t)(us.x & 0xffffu)) * di2 + b0.x, 0.f);
        r0.y = fmaxf(a1 + bf2f((ushort_t)(us.x >> 16)) * di2 + b0.y, 0.f);
        r0.z = fmaxf(a2 + bf2f((ushort_t)(us.y & 0xffffu)) * di2 + b0.z, 0.f);
        r0.w = fmaxf(a3 + bf2f((ushort_t)(us.y >> 16)) * di2 + b0.w, 0.f);
        r1.x = fmaxf(a4 + bf2f((ushort_t)(us.z & 0xffffu)) * di2 + b1.x, 0.f);
        r1.y = fmaxf(a5 + bf2f((ushort_t)(us.z >> 16)) * di2 + b1.y, 0.f);
        r1.z = fmaxf(a6 + bf2f((ushort_t)(us.w & 0xffffu)) * di2 + b1.z, 0.f);
        r1.w = fmaxf(a7 + bf2f((ushort_t)(us.w >> 16)) * di2 + b1.w, 0.f);
        *(float4*)&h1out[(size_t)v * FH + j * 8] = r0;
        *(float4*)&h1out[(size_t)v * FH + j * 8 + 4] = r1;
    }
#undef ACCUM
}

// ---- GEMM2: [NN,64] @ [64,16], bf16 output ----
__global__ __launch_bounds__(256) void k_gemm2(const float* __restrict__ h1,
                                               const float* __restrict__ W,
                                               ushort_t* __restrict__ h2) {
    __shared__ float Wl[FH * FO];
    for (int i = threadIdx.x; i < FH * FO / 4; i += 256) ((float4*)Wl)[i] = ((const float4*)W)[i];
    __syncthreads();
    int wave = (blockIdx.x * 256 + threadIdx.x) >> 6;
    int sub = (threadIdx.x & 63) >> 4;
    int j = threadIdx.x & 15;
    int node = wave * 4 + sub;
    if (node >= NN) return;
    float acc = 0.f;
    for (int k4 = 0; k4 < FH / 4; ++k4) {
        float4 hv = *(const float4*)&h1[node * FH + k4 * 4];
#pragma unroll
        for (int kk = 0; kk < 4; ++kk) acc += (&hv.x)[kk] * Wl[(k4 * 4 + kk) * FO + j];
    }
    h2[(size_t)node * FO + j] = f2bf(acc);
}

// ---- layer2 aggregate + bias + self-loop + log_softmax; bf16 h2p ----
__global__ __launch_bounds__(256) void k_gather2(const unsigned* __restrict__ rowstart,
                                                 const int* __restrict__ esrc,
                                                 const ushort_t* __restrict__ h2p,
                                                 const float* __restrict__ dinv,
                                                 const float* __restrict__ b,
                                                 float* __restrict__ out) {
    int v = (blockIdx.x * 256 + threadIdx.x) >> 6;
    int lane = threadIdx.x & 63;
    int g = lane >> 4, j = lane & 15;
    if (v >= NN) return;
    unsigned beg = rowstart[v], end = rowstart[v + 1];
    float dv = dinv[v];
    float acc = 0.f;
    unsigned i = beg + g;
    for (; i + 4 < end; i += 8) {
        int s0 = esrc[i], s1 = esrc[i + 4];
        float n0 = dinv[s0] * dv, n1 = dinv[s1] * dv;
        acc += bf2f(h2p[(size_t)s0 * FO + j]) * n0 + bf2f(h2p[(size_t)s1 * FO + j]) * n1;
    }
    for (; i < end; i += 4) {
        int s = esrc[i];
        acc += bf2f(h2p[(size_t)s * FO + j]) * (dinv[s] * dv);
    }
    acc += __shfl_xor(acc, 16);
    acc += __shfl_xor(acc, 32);
    float val = acc + bf2f(h2p[(size_t)v * FO + j]) * dv * dv + b[j];
    float m = val;
#pragma unroll
    for (int w = 1; w < 16; w <<= 1) m = fmaxf(m, __shfl_xor(m, w));
    float ex = expf(val - m);
    float ssum = ex;
#pragma unroll
    for (int w = 1; w < 16; w <<= 1) ssum += __shfl_xor(ssum, w);
    float res = val - (m + logf(ssum));
    if (g == 0) out[(size_t)v * FO + j] = res;
}

extern "C" void kernel_launch(void* const* d_in, const int* in_sizes, int n_in,
                              void* d_out, int out_size, void* d_ws, size_t ws_size,
                              hipStream_t stream) {
    const float* x = (const float*)d_in[0];
    const int* edges = (const int*)d_in[1];
    const float* W1 = (const float*)d_in[2];
    const float* b1 = (const float*)d_in[3];
    const float* W2 = (const float*)d_in[4];
    const float* b2 = (const float*)d_in[5];
    float* out = (float*)d_out;

    char* ws = (char*)d_ws;
    size_t off = 0;
    auto take = [&](size_t bytes) {
        void* p = ws + off;
        off += (bytes + 255) & ~(size_t)255;
        return p;
    };
    int* mode = (int*)take(256);
    unsigned* bcur = (unsigned*)take((size_t)NB * 4);
    unsigned* bbase = (unsigned*)take((size_t)NB * 4);
    unsigned* rowstart = (unsigned*)take((size_t)(NN + 1) * 4);
    float* dinv = (float*)take((size_t)NN * 4);
    int* esrc = (int*)take((size_t)NE * 4);
    ushort_t* h1p = (ushort_t*)take((size_t)NN * FH * 2);   // bf16
    float* h1 = (float*)take((size_t)NN * FH * 4);
    ushort_t* h2p = (ushort_t*)take((size_t)NN * FO * 2);   // bf16
    unsigned* staged = (unsigned*)h1;  // alias: staged (8.8 MB) dead before gather1 writes h1

    hipMemsetAsync(bcur, 0, (size_t)NB * 4, stream);
    k_detect<<<1, 64, 0, stream>>>(edges, mode);
    k_phaseA<<<ABLK, 256, 0, stream>>>(edges, mode, bcur, staged);
    k_bscan<<<1, 512, 0, stream>>>(bcur, bbase);
    k_phaseB<<<NB, 256, 0, stream>>>(staged, bcur, bbase, rowstart, esrc);
    k_dinv<<<(NN + 255) / 256, 256, 0, stream>>>(rowstart, dinv);
    k_gemm1<<<(NN + 63) / 64, 256, 0, stream>>>(x, W1, h1p);
    k_gather1<<<(size_t)NN * 64 / 256, 256, 0, stream>>>(rowstart, esrc, h1p, dinv, b1, h1);
    k_gemm2<<<(NN / 4 * 64) / 256, 256, 0, stream>>>(h1, W2, h2p);
    k_gather2<<<(size_t)NN * 64 / 256, 256, 0, stream>>>(rowstart, esrc, h2p, dinv, b2, out);
}

// Round 8
// 183.916 us; speedup vs baseline: 3.5996x; 1.0735x over previous
//
#include <hip/hip_runtime.h>
#include <math.h>

#define NN 100000
#define NE 1600000
#define FI 128
#define FH 64
#define FO 16
#define NB 392            // buckets of 256 nodes
#define BCAP 5632
#define AEPT 32
#define ACHUNK (256 * AEPT)
#define ABLK ((NE + ACHUNK - 1) / ACHUNK)  // 196

typedef unsigned short ushort_t;

__device__ __forceinline__ ushort_t f2bf(float f) {
    unsigned u = __float_as_uint(f);
    u = (u + 0x7fffu + ((u >> 16) & 1u)) >> 16;  // RNE
    return (ushort_t)u;
}
__device__ __forceinline__ float bf_lo(unsigned u) {
    return __uint_as_float(u << 16);
}
__device__ __forceinline__ float bf_hi(unsigned u) {
    return __uint_as_float(u & 0xffff0000u);
}

// ---- edge dtype detection ----
__global__ void k_detect(const int* __restrict__ edges, int* __restrict__ mode) {
    if (blockIdx.x == 0 && threadIdx.x == 0) {
        unsigned orv = 0;
        for (int i = 0; i < 16; ++i) orv |= (unsigned)edges[2 * i + 1];
        *mode = (orv == 0u) ? 1 : 0;  // 1 = int64
    }
}

__device__ __forceinline__ int load_dst(const int* edges, int mode, int e) {
    return mode ? edges[2 * (NE + e)] : edges[NE + e];
}
__device__ __forceinline__ int load_src(const int* edges, int mode, int e) {
    return mode ? edges[2 * e] : edges[e];
}

// ---- phase A: partition edges into 392 dst-buckets ----
__global__ __launch_bounds__(256) void k_phaseA(const int* __restrict__ edges,
                                                const int* __restrict__ mode,
                                                unsigned* __restrict__ bcur,
                                                unsigned* __restrict__ staged) {
    __shared__ unsigned hcnt[NB];
    __shared__ unsigned hrun[NB];
    __shared__ unsigned hcur[NB];
    const int m = *mode;
    for (int i = threadIdx.x; i < NB; i += 256) { hcnt[i] = 0; hcur[i] = 0; }
    __syncthreads();
    const int e0 = blockIdx.x * ACHUNK + threadIdx.x;
#pragma unroll
    for (int q = 0; q < AEPT; ++q) {
        int e = e0 + q * 256;
        if (e < NE) atomicAdd(&hcnt[load_dst(edges, m, e) >> 8], 1u);
    }
    __syncthreads();
    for (int i = threadIdx.x; i < NB; i += 256)
        hrun[i] = atomicAdd(&bcur[i], hcnt[i]);
    __syncthreads();
#pragma unroll
    for (int q = 0; q < AEPT; ++q) {
        int e = e0 + q * 256;
        if (e < NE) {
            int d = load_dst(edges, m, e);
            int s = load_src(edges, m, e);
            int b = d >> 8;
            unsigned r = hrun[b] + atomicAdd(&hcur[b], 1u);
            if (r < BCAP)
                staged[(size_t)b * BCAP + r] = ((unsigned)s << 8) | (unsigned)(d & 255);
        }
    }
}

__global__ void k_bscan(const unsigned* __restrict__ bcur, unsigned* __restrict__ bbase) {
    __shared__ unsigned tmp[512];
    int t = threadIdx.x;
    unsigned x = (t < NB) ? bcur[t] : 0u;
    tmp[t] = x;
    __syncthreads();
    for (int ofs = 1; ofs < 512; ofs <<= 1) {
        unsigned v = (t >= ofs) ? tmp[t - ofs] : 0u;
        __syncthreads();
        tmp[t] += v;
        __syncthreads();
    }
    if (t < NB) bbase[t] = tmp[t] - x;
}

// ---- phase B: per-bucket counting sort -> rowstart + src-only CSR ----
__global__ __launch_bounds__(256) void k_phaseB(const unsigned* __restrict__ staged,
                                                const unsigned* __restrict__ bcur,
                                                const unsigned* __restrict__ bbase,
                                                unsigned* __restrict__ rowstart,
                                                int* __restrict__ esrc) {
    __shared__ unsigned hist[256], hb[256], hcur[256], tmp[256];
    const int b = blockIdx.x;
    const int t = threadIdx.x;
    const unsigned cnt = min(bcur[b], (unsigned)BCAP);
    const unsigned base = bbase[b];
    hist[t] = 0;
    hcur[t] = 0;
    __syncthreads();
    const unsigned* sb = staged + (size_t)b * BCAP;
    for (unsigned i = t; i < cnt; i += 256) atomicAdd(&hist[sb[i] & 255u], 1u);
    __syncthreads();
    unsigned x = hist[t];
    tmp[t] = x;
    __syncthreads();
    for (int ofs = 1; ofs < 256; ofs <<= 1) {
        unsigned v = (t >= ofs) ? tmp[t - ofs] : 0u;
        __syncthreads();
        tmp[t] += v;
        __syncthreads();
    }
    hb[t] = tmp[t] - x;
    int v = b * 256 + t;
    if (v <= NN) rowstart[v] = base + hb[t];
    __syncthreads();
    for (unsigned i = t; i < cnt; i += 256) {
        unsigned p = sb[i];
        unsigned dlo = p & 255u;
        unsigned pos = base + hb[dlo] + atomicAdd(&hcur[dlo], 1u);
        esrc[pos] = (int)(p >> 8);
    }
}

__global__ void k_dinv(const unsigned* __restrict__ rowstart, float* __restrict__ dinv) {
    int v = blockIdx.x * blockDim.x + threadIdx.x;
    if (v < NN) dinv[v] = rsqrtf((float)(1u + rowstart[v + 1] - rowstart[v]));
}

// ---- GEMM1: LDS-tiled, bf16 output ----
__global__ __launch_bounds__(256) void k_gemm1(const float* __restrict__ x,
                                               const float* __restrict__ W,
                                               ushort_t* __restrict__ h) {
    __shared__ float Ws[FI][FH];
    __shared__ float As[64][64];

    const int tid = threadIdx.x;
    const int tm = tid & 15;
    const int tn = tid >> 4;
    const int node0 = blockIdx.x * 64;

#pragma unroll
    for (int p = 0; p < 8; ++p) {
        int q = tid + p * 256;
        int row = q >> 4, col4 = (q & 15) * 4;
        *(float4*)&Ws[row][col4] = *(const float4*)&W[row * FH + col4];
    }

    float acc[4][4];
#pragma unroll
    for (int i = 0; i < 4; ++i)
#pragma unroll
        for (int j = 0; j < 4; ++j) acc[i][j] = 0.f;

    const int snode = tid & 63;
    const int wq = tid >> 6;

    for (int s = 0; s < 2; ++s) {
        __syncthreads();
#pragma unroll
        for (int p = 0; p < 4; ++p) {
            int kk = wq * 4 + p * 16;
            float4 f4 = make_float4(0.f, 0.f, 0.f, 0.f);
            if (node0 + snode < NN)
                f4 = *(const float4*)&x[(size_t)(node0 + snode) * FI + s * 64 + kk];
            As[kk + 0][snode] = f4.x;
            As[kk + 1][snode] = f4.y;
            As[kk + 2][snode] = f4.z;
            As[kk + 3][snode] = f4.w;
        }
        __syncthreads();
#pragma unroll 8
        for (int kl = 0; kl < 64; ++kl) {
            float4 a4 = *(const float4*)&As[kl][tm * 4];
            float4 b4 = *(const float4*)&Ws[s * 64 + kl][tn * 4];
#pragma unroll
            for (int i = 0; i < 4; ++i)
#pragma unroll
                for (int j = 0; j < 4; ++j) acc[i][j] += (&a4.x)[i] * (&b4.x)[j];
        }
    }

#pragma unroll
    for (int i = 0; i < 4; ++i) {
        int node = node0 + tm * 4 + i;
        if (node < NN) {
            ushort4 r;
            r.x = f2bf(acc[i][0]);
            r.y = f2bf(acc[i][1]);
            r.z = f2bf(acc[i][2]);
            r.w = f2bf(acc[i][3]);
            *(ushort4*)&h[(size_t)node * FH + tn * 4] = r;
        }
    }
}

// ---- layer1 aggregate v3: 4 nodes/wave, 16 lanes/node, lane owns 4 features ----
__global__ __launch_bounds__(256) void k_gather1(const unsigned* __restrict__ rowstart,
                                                 const int* __restrict__ esrc,
                                                 const ushort_t* __restrict__ h1p,
                                                 const float* __restrict__ dinv,
                                                 const float* __restrict__ b,
                                                 float* __restrict__ h1out) {
    int wave = (blockIdx.x * 256 + threadIdx.x) >> 6;
    int lane = threadIdx.x & 63;
    int grp = lane >> 4;     // node within wave
    int fj = lane & 15;      // uint2 slot: features 4fj..4fj+3
    int v = wave * 4 + grp;
    if (v >= NN) return;
    const uint2* h2v = (const uint2*)h1p;  // row = 16 uint2
    unsigned beg = rowstart[v], end = rowstart[v + 1];
    float dv = dinv[v];
    float a0 = 0.f, a1 = 0.f, a2 = 0.f, a3 = 0.f;
    unsigned i = beg;
    for (; i + 1 < end; i += 2) {
        int s0 = esrc[i], s1 = esrc[i + 1];
        float n0 = dinv[s0] * dv, n1 = dinv[s1] * dv;
        uint2 u0 = h2v[(size_t)s0 * 16 + fj];
        uint2 u1 = h2v[(size_t)s1 * 16 + fj];
        a0 += bf_lo(u0.x) * n0 + bf_lo(u1.x) * n1;
        a1 += bf_hi(u0.x) * n0 + bf_hi(u1.x) * n1;
        a2 += bf_lo(u0.y) * n0 + bf_lo(u1.y) * n1;
        a3 += bf_hi(u0.y) * n0 + bf_hi(u1.y) * n1;
    }
    if (i < end) {
        int s = esrc[i];
        float n = dinv[s] * dv;
        uint2 u = h2v[(size_t)s * 16 + fj];
        a0 += bf_lo(u.x) * n;
        a1 += bf_hi(u.x) * n;
        a2 += bf_lo(u.y) * n;
        a3 += bf_hi(u.y) * n;
    }
    float di2 = dv * dv;
    uint2 us = h2v[(size_t)v * 16 + fj];
    float4 bb = ((const float4*)b)[fj];
    float4 r;
    r.x = fmaxf(a0 + bf_lo(us.x) * di2 + bb.x, 0.f);
    r.y = fmaxf(a1 + bf_hi(us.x) * di2 + bb.y, 0.f);
    r.z = fmaxf(a2 + bf_lo(us.y) * di2 + bb.z, 0.f);
    r.w = fmaxf(a3 + bf_hi(us.y) * di2 + bb.w, 0.f);
    *(float4*)&h1out[(size_t)v * FH + fj * 4] = r;
}

// ---- GEMM2: [NN,64] @ [64,16], bf16 output ----
__global__ __launch_bounds__(256) void k_gemm2(const float* __restrict__ h1,
                                               const float* __restrict__ W,
                                               ushort_t* __restrict__ h2) {
    __shared__ float Wl[FH * FO];
    for (int i = threadIdx.x; i < FH * FO / 4; i += 256) ((float4*)Wl)[i] = ((const float4*)W)[i];
    __syncthreads();
    int wave = (blockIdx.x * 256 + threadIdx.x) >> 6;
    int sub = (threadIdx.x & 63) >> 4;
    int j = threadIdx.x & 15;
    int node = wave * 4 + sub;
    if (node >= NN) return;
    float acc = 0.f;
    for (int k4 = 0; k4 < FH / 4; ++k4) {
        float4 hv = *(const float4*)&h1[node * FH + k4 * 4];
#pragma unroll
        for (int kk = 0; kk < 4; ++kk) acc += (&hv.x)[kk] * Wl[(k4 * 4 + kk) * FO + j];
    }
    h2[(size_t)node * FO + j] = f2bf(acc);
}

// ---- layer2 aggregate v2: 4 nodes/wave, 16 lanes/node, lane owns 1 feature ----
__global__ __launch_bounds__(256) void k_gather2(const unsigned* __restrict__ rowstart,
                                                 const int* __restrict__ esrc,
                                                 const ushort_t* __restrict__ h2p,
                                                 const float* __restrict__ dinv,
                                                 const float* __restrict__ b,
                                                 float* __restrict__ out) {
    int wave = (blockIdx.x * 256 + threadIdx.x) >> 6;
    int lane = threadIdx.x & 63;
    int grp = lane >> 4;
    int j = lane & 15;
    int v = wave * 4 + grp;
    if (v >= NN) return;
    unsigned beg = rowstart[v], end = rowstart[v + 1];
    float dv = dinv[v];
    float acc = 0.f;
    unsigned i = beg;
    for (; i + 1 < end; i += 2) {
        int s0 = esrc[i], s1 = esrc[i + 1];
        float n0 = dinv[s0] * dv, n1 = dinv[s1] * dv;
        float x0 = __uint_as_float((unsigned)h2p[(size_t)s0 * FO + j] << 16);
        float x1 = __uint_as_float((unsigned)h2p[(size_t)s1 * FO + j] << 16);
        acc += x0 * n0 + x1 * n1;
    }
    if (i < end) {
        int s = esrc[i];
        acc += __uint_as_float((unsigned)h2p[(size_t)s * FO + j] << 16) * (dinv[s] * dv);
    }
    float val = acc + __uint_as_float((unsigned)h2p[(size_t)v * FO + j] << 16) * dv * dv + b[j];
    float m = val;
#pragma unroll
    for (int w = 1; w < 16; w <<= 1) m = fmaxf(m, __shfl_xor(m, w));
    float ex = expf(val - m);
    float ssum = ex;
#pragma unroll
    for (int w = 1; w < 16; w <<= 1) ssum += __shfl_xor(ssum, w);
    float res = val - (m + logf(ssum));
    out[(size_t)v * FO + j] = res;
}

extern "C" void kernel_launch(void* const* d_in, const int* in_sizes, int n_in,
                              void* d_out, int out_size, void* d_ws, size_t ws_size,
                              hipStream_t stream) {
    const float* x = (const float*)d_in[0];
    const int* edges = (const int*)d_in[1];
    const float* W1 = (const float*)d_in[2];
    const float* b1 = (const float*)d_in[3];
    const float* W2 = (const float*)d_in[4];
    const float* b2 = (const float*)d_in[5];
    float* out = (float*)d_out;

    char* ws = (char*)d_ws;
    size_t off = 0;
    auto take = [&](size_t bytes) {
        void* p = ws + off;
        off += (bytes + 255) & ~(size_t)255;
        return p;
    };
    int* mode = (int*)take(256);
    unsigned* bcur = (unsigned*)take((size_t)NB * 4);
    unsigned* bbase = (unsigned*)take((size_t)NB * 4);
    unsigned* rowstart = (unsigned*)take((size_t)(NN + 1) * 4);
    float* dinv = (float*)take((size_t)NN * 4);
    int* esrc = (int*)take((size_t)NE * 4);
    ushort_t* h1p = (ushort_t*)take((size_t)NN * FH * 2);   // bf16
    float* h1 = (float*)take((size_t)NN * FH * 4);
    ushort_t* h2p = (ushort_t*)take((size_t)NN * FO * 2);   // bf16
    unsigned* staged = (unsigned*)h1;  // alias: staged dead before gather1 writes h1

    hipMemsetAsync(bcur, 0, (size_t)NB * 4, stream);
    k_detect<<<1, 64, 0, stream>>>(edges, mode);
    k_phaseA<<<ABLK, 256, 0, stream>>>(edges, mode, bcur, staged);
    k_bscan<<<1, 512, 0, stream>>>(bcur, bbase);
    k_phaseB<<<NB, 256, 0, stream>>>(staged, bcur, bbase, rowstart, esrc);
    k_dinv<<<(NN + 255) / 256, 256, 0, stream>>>(rowstart, dinv);
    k_gemm1<<<(NN + 63) / 64, 256, 0, stream>>>(x, W1, h1p);
    k_gather1<<<(NN + 15) / 16, 256, 0, stream>>>(rowstart, esrc, h1p, dinv, b1, h1);
    k_gemm2<<<(NN / 4 * 64) / 256, 256, 0, stream>>>(h1, W2, h2p);
    k_gather2<<<(NN + 15) / 16, 256, 0, stream>>>(rowstart, esrc, h2p, dinv, b2, out);
}

// Round 9
// 173.329 us; speedup vs baseline: 3.8195x; 1.0611x over previous
//
#include <hip/hip_runtime.h>
#include <math.h>

#define NN 100000
#define NE 1600000
#define FI 128
#define FH 64
#define FO 16
#define NB 392            // buckets of 256 nodes
#define BCAP 5632
#define AEPT 8
#define ACHUNK (256 * AEPT)                 // 2048 edges per phase-A block
#define ABLK ((NE + ACHUNK - 1) / ACHUNK)   // 782

typedef unsigned short ushort_t;

__device__ __forceinline__ ushort_t f2bf(float f) {
    unsigned u = __float_as_uint(f);
    u = (u + 0x7fffu + ((u >> 16) & 1u)) >> 16;  // RNE
    return (ushort_t)u;
}
__device__ __forceinline__ float bf_lo(unsigned u) {
    return __uint_as_float(u << 16);
}
__device__ __forceinline__ float bf_hi(unsigned u) {
    return __uint_as_float(u & 0xffff0000u);
}

// ---- edge dtype detection ----
__global__ void k_detect(const int* __restrict__ edges, int* __restrict__ mode) {
    if (blockIdx.x == 0 && threadIdx.x == 0) {
        unsigned orv = 0;
        for (int i = 0; i < 16; ++i) orv |= (unsigned)edges[2 * i + 1];
        *mode = (orv == 0u) ? 1 : 0;  // 1 = int64
    }
}

__device__ __forceinline__ int load_dst(const int* edges, int mode, int e) {
    return mode ? edges[2 * (NE + e)] : edges[NE + e];
}
__device__ __forceinline__ int load_src(const int* edges, int mode, int e) {
    return mode ? edges[2 * e] : edges[e];
}

// ---- phase A: partition edges into 392 dst-buckets ----
__global__ __launch_bounds__(256) void k_phaseA(const int* __restrict__ edges,
                                                const int* __restrict__ mode,
                                                unsigned* __restrict__ bcur,
                                                unsigned* __restrict__ staged) {
    __shared__ unsigned hcnt[NB];
    __shared__ unsigned hrun[NB];
    __shared__ unsigned hcur[NB];
    const int m = *mode;
    for (int i = threadIdx.x; i < NB; i += 256) { hcnt[i] = 0; hcur[i] = 0; }
    __syncthreads();
    const int e0 = blockIdx.x * ACHUNK + threadIdx.x;
#pragma unroll
    for (int q = 0; q < AEPT; ++q) {
        int e = e0 + q * 256;
        if (e < NE) atomicAdd(&hcnt[load_dst(edges, m, e) >> 8], 1u);
    }
    __syncthreads();
    for (int i = threadIdx.x; i < NB; i += 256)
        hrun[i] = atomicAdd(&bcur[i], hcnt[i]);
    __syncthreads();
#pragma unroll
    for (int q = 0; q < AEPT; ++q) {
        int e = e0 + q * 256;
        if (e < NE) {
            int d = load_dst(edges, m, e);
            int s = load_src(edges, m, e);
            int b = d >> 8;
            unsigned r = hrun[b] + atomicAdd(&hcur[b], 1u);
            if (r < BCAP)
                staged[(size_t)b * BCAP + r] = ((unsigned)s << 8) | (unsigned)(d & 255);
        }
    }
}

__global__ void k_bscan(const unsigned* __restrict__ bcur, unsigned* __restrict__ bbase) {
    __shared__ unsigned tmp[512];
    int t = threadIdx.x;
    unsigned x = (t < NB) ? bcur[t] : 0u;
    tmp[t] = x;
    __syncthreads();
    for (int ofs = 1; ofs < 512; ofs <<= 1) {
        unsigned v = (t >= ofs) ? tmp[t - ofs] : 0u;
        __syncthreads();
        tmp[t] += v;
        __syncthreads();
    }
    if (t < NB) bbase[t] = tmp[t] - x;
}

// ---- phase B: per-bucket counting sort -> rowstart + src-only CSR ----
__global__ __launch_bounds__(256) void k_phaseB(const unsigned* __restrict__ staged,
                                                const unsigned* __restrict__ bcur,
                                                const unsigned* __restrict__ bbase,
                                                unsigned* __restrict__ rowstart,
                                                int* __restrict__ esrc) {
    __shared__ unsigned hist[256], hb[256], hcur[256], tmp[256];
    const int b = blockIdx.x;
    const int t = threadIdx.x;
    const unsigned cnt = min(bcur[b], (unsigned)BCAP);
    const unsigned base = bbase[b];
    hist[t] = 0;
    hcur[t] = 0;
    __syncthreads();
    const unsigned* sb = staged + (size_t)b * BCAP;
    for (unsigned i = t; i < cnt; i += 256) atomicAdd(&hist[sb[i] & 255u], 1u);
    __syncthreads();
    unsigned x = hist[t];
    tmp[t] = x;
    __syncthreads();
    for (int ofs = 1; ofs < 256; ofs <<= 1) {
        unsigned v = (t >= ofs) ? tmp[t - ofs] : 0u;
        __syncthreads();
        tmp[t] += v;
        __syncthreads();
    }
    hb[t] = tmp[t] - x;
    int v = b * 256 + t;
    if (v <= NN) rowstart[v] = base + hb[t];
    __syncthreads();
    for (unsigned i = t; i < cnt; i += 256) {
        unsigned p = sb[i];
        unsigned dlo = p & 255u;
        unsigned pos = base + hb[dlo] + atomicAdd(&hcur[dlo], 1u);
        esrc[pos] = (int)(p >> 8);
    }
}

__global__ void k_dinv(const unsigned* __restrict__ rowstart, float* __restrict__ dinv) {
    int v = blockIdx.x * blockDim.x + threadIdx.x;
    if (v < NN) dinv[v] = rsqrtf((float)(1u + rowstart[v + 1] - rowstart[v]));
}

// ---- GEMM1: LDS-tiled, bf16 output ----
__global__ __launch_bounds__(256) void k_gemm1(const float* __restrict__ x,
                                               const float* __restrict__ W,
                                               ushort_t* __restrict__ h) {
    __shared__ float Ws[FI][FH];
    __shared__ float As[64][64];

    const int tid = threadIdx.x;
    const int tm = tid & 15;
    const int tn = tid >> 4;
    const int node0 = blockIdx.x * 64;

#pragma unroll
    for (int p = 0; p < 8; ++p) {
        int q = tid + p * 256;
        int row = q >> 4, col4 = (q & 15) * 4;
        *(float4*)&Ws[row][col4] = *(const float4*)&W[row * FH + col4];
    }

    float acc[4][4];
#pragma unroll
    for (int i = 0; i < 4; ++i)
#pragma unroll
        for (int j = 0; j < 4; ++j) acc[i][j] = 0.f;

    const int snode = tid & 63;
    const int wq = tid >> 6;

    for (int s = 0; s < 2; ++s) {
        __syncthreads();
#pragma unroll
        for (int p = 0; p < 4; ++p) {
            int kk = wq * 4 + p * 16;
            float4 f4 = make_float4(0.f, 0.f, 0.f, 0.f);
            if (node0 + snode < NN)
                f4 = *(const float4*)&x[(size_t)(node0 + snode) * FI + s * 64 + kk];
            As[kk + 0][snode] = f4.x;
            As[kk + 1][snode] = f4.y;
            As[kk + 2][snode] = f4.z;
            As[kk + 3][snode] = f4.w;
        }
        __syncthreads();
#pragma unroll 8
        for (int kl = 0; kl < 64; ++kl) {
            float4 a4 = *(const float4*)&As[kl][tm * 4];
            float4 b4 = *(const float4*)&Ws[s * 64 + kl][tn * 4];
#pragma unroll
            for (int i = 0; i < 4; ++i)
#pragma unroll
                for (int j = 0; j < 4; ++j) acc[i][j] += (&a4.x)[i] * (&b4.x)[j];
        }
    }

#pragma unroll
    for (int i = 0; i < 4; ++i) {
        int node = node0 + tm * 4 + i;
        if (node < NN) {
            ushort4 r;
            r.x = f2bf(acc[i][0]);
            r.y = f2bf(acc[i][1]);
            r.z = f2bf(acc[i][2]);
            r.w = f2bf(acc[i][3]);
            *(ushort4*)&h[(size_t)node * FH + tn * 4] = r;
        }
    }
}

// ---- layer1 aggregate: 4 nodes/wave, 16 lanes/node, lane owns 4 feats, unroll 4 ----
__global__ __launch_bounds__(256) void k_gather1(const unsigned* __restrict__ rowstart,
                                                 const int* __restrict__ esrc,
                                                 const ushort_t* __restrict__ h1p,
                                                 const float* __restrict__ dinv,
                                                 const float* __restrict__ b,
                                                 float* __restrict__ h1out) {
    int wave = (blockIdx.x * 256 + threadIdx.x) >> 6;
    int lane = threadIdx.x & 63;
    int grp = lane >> 4;     // node within wave
    int fj = lane & 15;      // uint2 slot: features 4fj..4fj+3
    int v = wave * 4 + grp;
    if (v >= NN) return;
    const uint2* h2v = (const uint2*)h1p;  // row = 16 uint2
    unsigned beg = rowstart[v], end = rowstart[v + 1];
    float dv = dinv[v];
    float a0 = 0.f, a1 = 0.f, a2 = 0.f, a3 = 0.f;
    unsigned i = beg;
    for (; i + 3 < end; i += 4) {
        int s0 = esrc[i], s1 = esrc[i + 1], s2 = esrc[i + 2], s3 = esrc[i + 3];
        float n0 = dinv[s0] * dv, n1 = dinv[s1] * dv;
        float n2 = dinv[s2] * dv, n3 = dinv[s3] * dv;
        uint2 u0 = h2v[(size_t)s0 * 16 + fj];
        uint2 u1 = h2v[(size_t)s1 * 16 + fj];
        uint2 u2 = h2v[(size_t)s2 * 16 + fj];
        uint2 u3 = h2v[(size_t)s3 * 16 + fj];
        a0 += bf_lo(u0.x) * n0 + bf_lo(u1.x) * n1 + bf_lo(u2.x) * n2 + bf_lo(u3.x) * n3;
        a1 += bf_hi(u0.x) * n0 + bf_hi(u1.x) * n1 + bf_hi(u2.x) * n2 + bf_hi(u3.x) * n3;
        a2 += bf_lo(u0.y) * n0 + bf_lo(u1.y) * n1 + bf_lo(u2.y) * n2 + bf_lo(u3.y) * n3;
        a3 += bf_hi(u0.y) * n0 + bf_hi(u1.y) * n1 + bf_hi(u2.y) * n2 + bf_hi(u3.y) * n3;
    }
    for (; i < end; ++i) {
        int s = esrc[i];
        float n = dinv[s] * dv;
        uint2 u = h2v[(size_t)s * 16 + fj];
        a0 += bf_lo(u.x) * n;
        a1 += bf_hi(u.x) * n;
        a2 += bf_lo(u.y) * n;
        a3 += bf_hi(u.y) * n;
    }
    float di2 = dv * dv;
    uint2 us = h2v[(size_t)v * 16 + fj];
    float4 bb = ((const float4*)b)[fj];
    float4 r;
    r.x = fmaxf(a0 + bf_lo(us.x) * di2 + bb.x, 0.f);
    r.y = fmaxf(a1 + bf_hi(us.x) * di2 + bb.y, 0.f);
    r.z = fmaxf(a2 + bf_lo(us.y) * di2 + bb.z, 0.f);
    r.w = fmaxf(a3 + bf_hi(us.y) * di2 + bb.w, 0.f);
    *(float4*)&h1out[(size_t)v * FH + fj * 4] = r;
}

// ---- GEMM2: [NN,64] @ [64,16], bf16 output ----
__global__ __launch_bounds__(256) void k_gemm2(const float* __restrict__ h1,
                                               const float* __restrict__ W,
                                               ushort_t* __restrict__ h2) {
    __shared__ float Wl[FH * FO];
    for (int i = threadIdx.x; i < FH * FO / 4; i += 256) ((float4*)Wl)[i] = ((const float4*)W)[i];
    __syncthreads();
    int wave = (blockIdx.x * 256 + threadIdx.x) >> 6;
    int sub = (threadIdx.x & 63) >> 4;
    int j = threadIdx.x & 15;
    int node = wave * 4 + sub;
    if (node >= NN) return;
    float acc = 0.f;
    for (int k4 = 0; k4 < FH / 4; ++k4) {
        float4 hv = *(const float4*)&h1[node * FH + k4 * 4];
#pragma unroll
        for (int kk = 0; kk < 4; ++kk) acc += (&hv.x)[kk] * Wl[(k4 * 4 + kk) * FO + j];
    }
    h2[(size_t)node * FO + j] = f2bf(acc);
}

// ---- layer2 aggregate: 4 nodes/wave, 16 lanes/node, 1 feat/lane, unroll 4 ----
__global__ __launch_bounds__(256) void k_gather2(const unsigned* __restrict__ rowstart,
                                                 const int* __restrict__ esrc,
                                                 const ushort_t* __restrict__ h2p,
                                                 const float* __restrict__ dinv,
                                                 const float* __restrict__ b,
                                                 float* __restrict__ out) {
    int wave = (blockIdx.x * 256 + threadIdx.x) >> 6;
    int lane = threadIdx.x & 63;
    int grp = lane >> 4;
    int j = lane & 15;
    int v = wave * 4 + grp;
    if (v >= NN) return;
    unsigned beg = rowstart[v], end = rowstart[v + 1];
    float dv = dinv[v];
    float acc = 0.f;
    unsigned i = beg;
    for (; i + 3 < end; i += 4) {
        int s0 = esrc[i], s1 = esrc[i + 1], s2 = esrc[i + 2], s3 = esrc[i + 3];
        float n0 = dinv[s0] * dv, n1 = dinv[s1] * dv;
        float n2 = dinv[s2] * dv, n3 = dinv[s3] * dv;
        float x0 = __uint_as_float((unsigned)h2p[(size_t)s0 * FO + j] << 16);
        float x1 = __uint_as_float((unsigned)h2p[(size_t)s1 * FO + j] << 16);
        float x2 = __uint_as_float((unsigned)h2p[(size_t)s2 * FO + j] << 16);
        float x3 = __uint_as_float((unsigned)h2p[(size_t)s3 * FO + j] << 16);
        acc += x0 * n0 + x1 * n1 + x2 * n2 + x3 * n3;
    }
    for (; i < end; ++i) {
        int s = esrc[i];
        acc += __uint_as_float((unsigned)h2p[(size_t)s * FO + j] << 16) * (dinv[s] * dv);
    }
    float val = acc + __uint_as_float((unsigned)h2p[(size_t)v * FO + j] << 16) * dv * dv + b[j];
    float m = val;
#pragma unroll
    for (int w = 1; w < 16; w <<= 1) m = fmaxf(m, __shfl_xor(m, w));
    float ex = expf(val - m);
    float ssum = ex;
#pragma unroll
    for (int w = 1; w < 16; w <<= 1) ssum += __shfl_xor(ssum, w);
    float res = val - (m + logf(ssum));
    out[(size_t)v * FO + j] = res;
}

extern "C" void kernel_launch(void* const* d_in, const int* in_sizes, int n_in,
                              void* d_out, int out_size, void* d_ws, size_t ws_size,
                              hipStream_t stream) {
    const float* x = (const float*)d_in[0];
    const int* edges = (const int*)d_in[1];
    const float* W1 = (const float*)d_in[2];
    const float* b1 = (const float*)d_in[3];
    const float* W2 = (const float*)d_in[4];
    const float* b2 = (const float*)d_in[5];
    float* out = (float*)d_out;

    char* ws = (char*)d_ws;
    size_t off = 0;
    auto take = [&](size_t bytes) {
        void* p = ws + off;
        off += (bytes + 255) & ~(size_t)255;
        return p;
    };
    int* mode = (int*)take(256);
    unsigned* bcur = (unsigned*)take((size_t)NB * 4);
    unsigned* bbase = (unsigned*)take((size_t)NB * 4);
    unsigned* rowstart = (unsigned*)take((size_t)(NN + 1) * 4);
    float* dinv = (float*)take((size_t)NN * 4);
    int* esrc = (int*)take((size_t)NE * 4);
    ushort_t* h1p = (ushort_t*)take((size_t)NN * FH * 2);   // bf16
    float* h1 = (float*)take((size_t)NN * FH * 4);
    ushort_t* h2p = (ushort_t*)take((size_t)NN * FO * 2);   // bf16
    unsigned* staged = (unsigned*)h1;  // alias: staged dead before gather1 writes h1

    hipMemsetAsync(bcur, 0, (size_t)NB * 4, stream);
    k_detect<<<1, 64, 0, stream>>>(edges, mode);
    k_phaseA<<<ABLK, 256, 0, stream>>>(edges, mode, bcur, staged);
    k_bscan<<<1, 512, 0, stream>>>(bcur, bbase);
    k_phaseB<<<NB, 256, 0, stream>>>(staged, bcur, bbase, rowstart, esrc);
    k_dinv<<<(NN + 255) / 256, 256, 0, stream>>>(rowstart, dinv);
    k_gemm1<<<(NN + 63) / 64, 256, 0, stream>>>(x, W1, h1p);
    k_gather1<<<(NN + 15) / 16, 256, 0, stream>>>(rowstart, esrc, h1p, dinv, b1, h1);
    k_gemm2<<<(NN / 4 * 64) / 256, 256, 0, stream>>>(h1, W2, h2p);
    k_gather2<<<(NN + 15) / 16, 256, 0, stream>>>(rowstart, esrc, h2p, dinv, b2, out);
}

// Round 10
// 147.778 us; speedup vs baseline: 4.4798x; 1.1729x over previous
//
#include <hip/hip_runtime.h>
#include <math.h>

#define NN 100000
#define NE 1600000
#define FI 128
#define FH 64
#define FO 16
#define NB 392            // buckets of 256 nodes
#define BCAP 5632
#define AEPT 16
#define ACHUNK (256 * AEPT)                 // 4096 edges per phase-A block
#define ABLK ((NE + ACHUNK - 1) / ACHUNK)   // 391

typedef unsigned short ushort_t;

__device__ __forceinline__ ushort_t f2bf(float f) {
    unsigned u = __float_as_uint(f);
    u = (u + 0x7fffu + ((u >> 16) & 1u)) >> 16;  // RNE
    return (ushort_t)u;
}
__device__ __forceinline__ float bf_lo(unsigned u) {
    return __uint_as_float(u << 16);
}
__device__ __forceinline__ float bf_hi(unsigned u) {
    return __uint_as_float(u & 0xffff0000u);
}

// ---- edge dtype detection ----
__global__ void k_detect(const int* __restrict__ edges, int* __restrict__ mode) {
    if (blockIdx.x == 0 && threadIdx.x == 0) {
        unsigned orv = 0;
        for (int i = 0; i < 16; ++i) orv |= (unsigned)edges[2 * i + 1];
        *mode = (orv == 0u) ? 1 : 0;  // 1 = int64
    }
}

__device__ __forceinline__ int load_dst(const int* edges, int mode, int e) {
    return mode ? edges[2 * (NE + e)] : edges[NE + e];
}
__device__ __forceinline__ int load_src(const int* edges, int mode, int e) {
    return mode ? edges[2 * e] : edges[e];
}

// ---- phase A v2: single edge pass, LDS counting sort, coalesced flush ----
__global__ __launch_bounds__(256) void k_phaseA(const int* __restrict__ edges,
                                                const int* __restrict__ mode,
                                                unsigned* __restrict__ bcur,
                                                unsigned* __restrict__ staged) {
    __shared__ unsigned pay_lds[ACHUNK];       // 16 KB, payload sorted by bucket
    __shared__ ushort_t bkt_lds[ACHUNK];       // 8 KB, bucket of sorted slot
    __shared__ unsigned hcnt[NB], hb[NB], dlt[NB], hcur[NB];
    __shared__ unsigned sc[512];

    const int m = *mode;
    const int t = threadIdx.x;
    const int base_e = blockIdx.x * ACHUNK;
    const int total = min(ACHUNK, NE - base_e);

    for (int i = t; i < NB; i += 256) { hcnt[i] = 0; hcur[i] = 0; }
    __syncthreads();

    // pass 1: load edges into registers, histogram buckets
    unsigned pay[AEPT];
    ushort_t bk[AEPT];
#pragma unroll
    for (int q = 0; q < AEPT; ++q) {
        int e = base_e + t + q * 256;
        pay[q] = 0;
        bk[q] = 0xffff;
        if (e < NE) {
            int d = load_dst(edges, m, e);
            int s = load_src(edges, m, e);
            pay[q] = ((unsigned)s << 8) | (unsigned)(d & 255);
            bk[q] = (ushort_t)(d >> 8);
            atomicAdd(&hcnt[d >> 8], 1u);
        }
    }
    __syncthreads();

    // global reservation per bucket
    for (int i = t; i < NB; i += 256) dlt[i] = atomicAdd(&bcur[i], hcnt[i]);  // dlt = hrun for now
    // block-level exclusive scan of hcnt -> hb  (Hillis-Steele over 512 slots)
    sc[t] = (t < NB) ? hcnt[t] : 0u;
    sc[t + 256] = (t + 256 < NB) ? hcnt[t + 256] : 0u;
    __syncthreads();
    for (int ofs = 1; ofs < 512; ofs <<= 1) {
        unsigned v0 = (t >= ofs) ? sc[t - ofs] : 0u;
        unsigned v1 = (t + 256 >= ofs) ? sc[t + 256 - ofs] : 0u;
        __syncthreads();
        sc[t] += v0;
        sc[t + 256] += v1;
        __syncthreads();
    }
    for (int i = t; i < NB; i += 256) hb[i] = sc[i] - hcnt[i];
    __syncthreads();
    // dlt[b] = hrun[b] - hb[b]
    for (int i = t; i < NB; i += 256) dlt[i] = dlt[i] - hb[i];
    __syncthreads();

    // pass 2: rank into LDS-sorted order
#pragma unroll
    for (int q = 0; q < AEPT; ++q) {
        if (bk[q] != 0xffff) {
            unsigned b = bk[q];
            unsigned r = atomicAdd(&hcur[b], 1u);
            unsigned idx = hb[b] + r;
            pay_lds[idx] = pay[q];
            bkt_lds[idx] = (ushort_t)b;
        }
    }
    __syncthreads();

    // flush: consecutive slots -> consecutive staged addresses within bucket runs
    for (int i = t; i < total; i += 256) {
        unsigned b = bkt_lds[i];
        unsigned within = (unsigned)i + dlt[b];   // position within bucket slice
        if (within < BCAP)
            staged[(size_t)b * BCAP + within] = pay_lds[i];
    }
}

__global__ void k_bscan(const unsigned* __restrict__ bcur, unsigned* __restrict__ bbase) {
    __shared__ unsigned tmp[512];
    int t = threadIdx.x;
    unsigned x = (t < NB) ? bcur[t] : 0u;
    tmp[t] = x;
    __syncthreads();
    for (int ofs = 1; ofs < 512; ofs <<= 1) {
        unsigned v = (t >= ofs) ? tmp[t - ofs] : 0u;
        __syncthreads();
        tmp[t] += v;
        __syncthreads();
    }
    if (t < NB) bbase[t] = tmp[t] - x;
}

// ---- phase B: per-bucket counting sort -> rowstart + src-only CSR ----
__global__ __launch_bounds__(256) void k_phaseB(const unsigned* __restrict__ staged,
                                                const unsigned* __restrict__ bcur,
                                                const unsigned* __restrict__ bbase,
                                                unsigned* __restrict__ rowstart,
                                                int* __restrict__ esrc) {
    __shared__ unsigned hist[256], hb[256], hcur[256], tmp[256];
    const int b = blockIdx.x;
    const int t = threadIdx.x;
    const unsigned cnt = min(bcur[b], (unsigned)BCAP);
    const unsigned base = bbase[b];
    hist[t] = 0;
    hcur[t] = 0;
    __syncthreads();
    const unsigned* sb = staged + (size_t)b * BCAP;
    for (unsigned i = t; i < cnt; i += 256) atomicAdd(&hist[sb[i] & 255u], 1u);
    __syncthreads();
    unsigned x = hist[t];
    tmp[t] = x;
    __syncthreads();
    for (int ofs = 1; ofs < 256; ofs <<= 1) {
        unsigned v = (t >= ofs) ? tmp[t - ofs] : 0u;
        __syncthreads();
        tmp[t] += v;
        __syncthreads();
    }
    hb[t] = tmp[t] - x;
    int v = b * 256 + t;
    if (v <= NN) rowstart[v] = base + hb[t];
    __syncthreads();
    for (unsigned i = t; i < cnt; i += 256) {
        unsigned p = sb[i];
        unsigned dlo = p & 255u;
        unsigned pos = base + hb[dlo] + atomicAdd(&hcur[dlo], 1u);
        esrc[pos] = (int)(p >> 8);
    }
}

__global__ void k_dinv(const unsigned* __restrict__ rowstart, float* __restrict__ dinv) {
    int v = blockIdx.x * blockDim.x + threadIdx.x;
    if (v < NN) dinv[v] = rsqrtf((float)(1u + rowstart[v + 1] - rowstart[v]));
}

// ---- GEMM1: LDS-tiled, bf16 output ----
__global__ __launch_bounds__(256) void k_gemm1(const float* __restrict__ x,
                                               const float* __restrict__ W,
                                               ushort_t* __restrict__ h) {
    __shared__ float Ws[FI][FH];
    __shared__ float As[64][64];

    const int tid = threadIdx.x;
    const int tm = tid & 15;
    const int tn = tid >> 4;
    const int node0 = blockIdx.x * 64;

#pragma unroll
    for (int p = 0; p < 8; ++p) {
        int q = tid + p * 256;
        int row = q >> 4, col4 = (q & 15) * 4;
        *(float4*)&Ws[row][col4] = *(const float4*)&W[row * FH + col4];
    }

    float acc[4][4];
#pragma unroll
    for (int i = 0; i < 4; ++i)
#pragma unroll
        for (int j = 0; j < 4; ++j) acc[i][j] = 0.f;

    const int snode = tid & 63;
    const int wq = tid >> 6;

    for (int s = 0; s < 2; ++s) {
        __syncthreads();
#pragma unroll
        for (int p = 0; p < 4; ++p) {
            int kk = wq * 4 + p * 16;
            float4 f4 = make_float4(0.f, 0.f, 0.f, 0.f);
            if (node0 + snode < NN)
                f4 = *(const float4*)&x[(size_t)(node0 + snode) * FI + s * 64 + kk];
            As[kk + 0][snode] = f4.x;
            As[kk + 1][snode] = f4.y;
            As[kk + 2][snode] = f4.z;
            As[kk + 3][snode] = f4.w;
        }
        __syncthreads();
#pragma unroll 8
        for (int kl = 0; kl < 64; ++kl) {
            float4 a4 = *(const float4*)&As[kl][tm * 4];
            float4 b4 = *(const float4*)&Ws[s * 64 + kl][tn * 4];
#pragma unroll
            for (int i = 0; i < 4; ++i)
#pragma unroll
                for (int j = 0; j < 4; ++j) acc[i][j] += (&a4.x)[i] * (&b4.x)[j];
        }
    }

#pragma unroll
    for (int i = 0; i < 4; ++i) {
        int node = node0 + tm * 4 + i;
        if (node < NN) {
            ushort4 r;
            r.x = f2bf(acc[i][0]);
            r.y = f2bf(acc[i][1]);
            r.z = f2bf(acc[i][2]);
            r.w = f2bf(acc[i][3]);
            *(ushort4*)&h[(size_t)node * FH + tn * 4] = r;
        }
    }
}

// ---- fused layer1 aggregate + GEMM2: 4 nodes/wave, 16 lanes/node ----
// lane fj owns h1 feats 4fj..4fj+3; epilogue multiplies into W2 (LDS, transposed)
// and butterfly-reduces so lane fj holds output j=fj; writes h2p bf16 directly.
__global__ __launch_bounds__(256) void k_gather1f(const unsigned* __restrict__ rowstart,
                                                  const int* __restrict__ esrc,
                                                  const ushort_t* __restrict__ h1p,
                                                  const float* __restrict__ dinv,
                                                  const float* __restrict__ b1,
                                                  const float* __restrict__ W2,
                                                  ushort_t* __restrict__ h2p) {
    __shared__ float Ws2t[FO][FH];  // Ws2t[j][k] = W2[k][j], 4 KB
    {
        int t = threadIdx.x;
#pragma unroll
        for (int i = 0; i < 4; ++i) {
            int q = t * 4 + i;          // linear index into W2 [64][16]
            int k = q >> 4, j = q & 15;
            Ws2t[j][k] = W2[q];
        }
    }
    __syncthreads();

    int wave = (blockIdx.x * 256 + threadIdx.x) >> 6;
    int lane = threadIdx.x & 63;
    int grp = lane >> 4;     // node within wave
    int fj = lane & 15;      // feature slot: feats 4fj..4fj+3
    int v = wave * 4 + grp;
    if (v >= NN) return;

    const uint2* h2v = (const uint2*)h1p;  // row = 16 uint2
    unsigned beg = rowstart[v], end = rowstart[v + 1];
    float dv = dinv[v];
    float a0 = 0.f, a1 = 0.f, a2 = 0.f, a3 = 0.f;
    unsigned i = beg;
    for (; i + 3 < end; i += 4) {
        int s0 = esrc[i], s1 = esrc[i + 1], s2 = esrc[i + 2], s3 = esrc[i + 3];
        float n0 = dinv[s0] * dv, n1 = dinv[s1] * dv;
        float n2 = dinv[s2] * dv, n3 = dinv[s3] * dv;
        uint2 u0 = h2v[(size_t)s0 * 16 + fj];
        uint2 u1 = h2v[(size_t)s1 * 16 + fj];
        uint2 u2 = h2v[(size_t)s2 * 16 + fj];
        uint2 u3 = h2v[(size_t)s3 * 16 + fj];
        a0 += bf_lo(u0.x) * n0 + bf_lo(u1.x) * n1 + bf_lo(u2.x) * n2 + bf_lo(u3.x) * n3;
        a1 += bf_hi(u0.x) * n0 + bf_hi(u1.x) * n1 + bf_hi(u2.x) * n2 + bf_hi(u3.x) * n3;
        a2 += bf_lo(u0.y) * n0 + bf_lo(u1.y) * n1 + bf_lo(u2.y) * n2 + bf_lo(u3.y) * n3;
        a3 += bf_hi(u0.y) * n0 + bf_hi(u1.y) * n1 + bf_hi(u2.y) * n2 + bf_hi(u3.y) * n3;
    }
    for (; i < end; ++i) {
        int s = esrc[i];
        float n = dinv[s] * dv;
        uint2 u = h2v[(size_t)s * 16 + fj];
        a0 += bf_lo(u.x) * n;
        a1 += bf_hi(u.x) * n;
        a2 += bf_lo(u.y) * n;
        a3 += bf_hi(u.y) * n;
    }
    // finish layer1: self loop + bias + relu (f32 in regs)
    float di2 = dv * dv;
    uint2 us = h2v[(size_t)v * 16 + fj];
    float4 bb = ((const float4*)b1)[fj];
    float r0 = fmaxf(a0 + bf_lo(us.x) * di2 + bb.x, 0.f);
    float r1 = fmaxf(a1 + bf_hi(us.x) * di2 + bb.y, 0.f);
    float r2 = fmaxf(a2 + bf_lo(us.y) * di2 + bb.z, 0.f);
    float r3 = fmaxf(a3 + bf_hi(us.y) * di2 + bb.w, 0.f);

    // GEMM2 partials: p[j] = sum over this lane's 4 feats
    float p[16];
#pragma unroll
    for (int j = 0; j < 16; ++j) {
        float4 w = *(const float4*)&Ws2t[j][fj * 4];
        p[j] = r0 * w.x + r1 * w.y + r2 * w.z + r3 * w.w;
    }
    // distributive butterfly over 16-lane group: lane fj ends with sum for j=fj
    bool c0 = (fj & 1) != 0;
    float q8[8];
#pragma unroll
    for (int k = 0; k < 8; ++k) {
        float sent = c0 ? p[2 * k] : p[2 * k + 1];
        float kept = c0 ? p[2 * k + 1] : p[2 * k];
        q8[k] = kept + __shfl_xor(sent, 1);
    }
    bool c1 = (fj & 2) != 0;
    float q4[4];
#pragma unroll
    for (int k = 0; k < 4; ++k) {
        float sent = c1 ? q8[2 * k] : q8[2 * k + 1];
        float kept = c1 ? q8[2 * k + 1] : q8[2 * k];
        q4[k] = kept + __shfl_xor(sent, 2);
    }
    bool c2 = (fj & 4) != 0;
    float q2[2];
#pragma unroll
    for (int k = 0; k < 2; ++k) {
        float sent = c2 ? q4[2 * k] : q4[2 * k + 1];
        float kept = c2 ? q4[2 * k + 1] : q4[2 * k];
        q2[k] = kept + __shfl_xor(sent, 4);
    }
    bool c3 = (fj & 8) != 0;
    {
        float sent = c3 ? q2[0] : q2[1];
        float kept = c3 ? q2[1] : q2[0];
        float fin = kept + __shfl_xor(sent, 8);
        h2p[(size_t)v * FO + fj] = f2bf(fin);
    }
}

// ---- layer2 aggregate: 4 nodes/wave, 16 lanes/node, 1 feat/lane, unroll 4 ----
__global__ __launch_bounds__(256) void k_gather2(const unsigned* __restrict__ rowstart,
                                                 const int* __restrict__ esrc,
                                                 const ushort_t* __restrict__ h2p,
                                                 const float* __restrict__ dinv,
                                                 const float* __restrict__ b,
                                                 float* __restrict__ out) {
    int wave = (blockIdx.x * 256 + threadIdx.x) >> 6;
    int lane = threadIdx.x & 63;
    int grp = lane >> 4;
    int j = lane & 15;
    int v = wave * 4 + grp;
    if (v >= NN) return;
    unsigned beg = rowstart[v], end = rowstart[v + 1];
    float dv = dinv[v];
    float acc = 0.f;
    unsigned i = beg;
    for (; i + 3 < end; i += 4) {
        int s0 = esrc[i], s1 = esrc[i + 1], s2 = esrc[i + 2], s3 = esrc[i + 3];
        float n0 = dinv[s0] * dv, n1 = dinv[s1] * dv;
        float n2 = dinv[s2] * dv, n3 = dinv[s3] * dv;
        float x0 = __uint_as_float((unsigned)h2p[(size_t)s0 * FO + j] << 16);
        float x1 = __uint_as_float((unsigned)h2p[(size_t)s1 * FO + j] << 16);
        float x2 = __uint_as_float((unsigned)h2p[(size_t)s2 * FO + j] << 16);
        float x3 = __uint_as_float((unsigned)h2p[(size_t)s3 * FO + j] << 16);
        acc += x0 * n0 + x1 * n1 + x2 * n2 + x3 * n3;
    }
    for (; i < end; ++i) {
        int s = esrc[i];
        acc += __uint_as_float((unsigned)h2p[(size_t)s * FO + j] << 16) * (dinv[s] * dv);
    }
    float val = acc + __uint_as_float((unsigned)h2p[(size_t)v * FO + j] << 16) * dv * dv + b[j];
    float m = val;
#pragma unroll
    for (int w = 1; w < 16; w <<= 1) m = fmaxf(m, __shfl_xor(m, w));
    float ex = expf(val - m);
    float ssum = ex;
#pragma unroll
    for (int w = 1; w < 16; w <<= 1) ssum += __shfl_xor(ssum, w);
    float res = val - (m + logf(ssum));
    out[(size_t)v * FO + j] = res;
}

extern "C" void kernel_launch(void* const* d_in, const int* in_sizes, int n_in,
                              void* d_out, int out_size, void* d_ws, size_t ws_size,
                              hipStream_t stream) {
    const float* x = (const float*)d_in[0];
    const int* edges = (const int*)d_in[1];
    const float* W1 = (const float*)d_in[2];
    const float* b1 = (const float*)d_in[3];
    const float* W2 = (const float*)d_in[4];
    const float* b2 = (const float*)d_in[5];
    float* out = (float*)d_out;

    char* ws = (char*)d_ws;
    size_t off = 0;
    auto take = [&](size_t bytes) {
        void* p = ws + off;
        off += (bytes + 255) & ~(size_t)255;
        return p;
    };
    int* mode = (int*)take(256);
    unsigned* bcur = (unsigned*)take((size_t)NB * 4);
    unsigned* bbase = (unsigned*)take((size_t)NB * 4);
    unsigned* rowstart = (unsigned*)take((size_t)(NN + 1) * 4);
    float* dinv = (float*)take((size_t)NN * 4);
    int* esrc = (int*)take((size_t)NE * 4);
    ushort_t* h1p = (ushort_t*)take((size_t)NN * FH * 2);   // bf16
    ushort_t* h2p = (ushort_t*)take((size_t)NN * FO * 2);   // bf16
    unsigned* staged = (unsigned*)take((size_t)NB * BCAP * 4);  // 8.8 MB

    hipMemsetAsync(bcur, 0, (size_t)NB * 4, stream);
    k_detect<<<1, 64, 0, stream>>>(edges, mode);
    k_phaseA<<<ABLK, 256, 0, stream>>>(edges, mode, bcur, staged);
    k_bscan<<<1, 512, 0, stream>>>(bcur, bbase);
    k_phaseB<<<NB, 256, 0, stream>>>(staged, bcur, bbase, rowstart, esrc);
    k_dinv<<<(NN + 255) / 256, 256, 0, stream>>>(rowstart, dinv);
    k_gemm1<<<(NN + 63) / 64, 256, 0, stream>>>(x, W1, h1p);
    k_gather1f<<<(NN + 15) / 16, 256, 0, stream>>>(rowstart, esrc, h1p, dinv, b1, W2, h2p);
    k_gather2<<<(NN + 15) / 16, 256, 0, stream>>>(rowstart, esrc, h2p, dinv, b2, out);
}

// Round 11
// 134.675 us; speedup vs baseline: 4.9157x; 1.0973x over previous
//
#include <hip/hip_runtime.h>
#include <math.h>

#define NN 100000
#define NE 1600000
#define FI 128
#define FH 64
#define FO 16
#define NB 392            // buckets of 256 nodes
#define BCAP 5632
#define AEPT 16
#define ACHUNK (256 * AEPT)                 // 4096 edges per phase-A block
#define ABLK ((NE + ACHUNK - 1) / ACHUNK)   // 391

typedef unsigned short ushort_t;
typedef __attribute__((ext_vector_type(8))) short bf16x8;
typedef __attribute__((ext_vector_type(4))) float f32x4;

__device__ __forceinline__ ushort_t f2bf(float f) {
    unsigned u = __float_as_uint(f);
    u = (u + 0x7fffu + ((u >> 16) & 1u)) >> 16;  // RNE
    return (ushort_t)u;
}
__device__ __forceinline__ float bf_lo(unsigned u) {
    return __uint_as_float(u << 16);
}
__device__ __forceinline__ float bf_hi(unsigned u) {
    return __uint_as_float(u & 0xffff0000u);
}

__device__ __forceinline__ int load_dst(const int* edges, int mode, int e) {
    return mode ? edges[2 * (NE + e)] : edges[NE + e];
}
__device__ __forceinline__ int load_src(const int* edges, int mode, int e) {
    return mode ? edges[2 * e] : edges[e];
}

// ---- phase A: single edge pass, LDS counting sort, coalesced flush ----
// (edge dtype detection inlined: per-block, 16 loads)
__global__ __launch_bounds__(256) void k_phaseA(const int* __restrict__ edges,
                                                unsigned* __restrict__ bcur,
                                                unsigned* __restrict__ staged) {
    __shared__ unsigned pay_lds[ACHUNK];       // 16 KB
    __shared__ ushort_t bkt_lds[ACHUNK];       // 8 KB
    __shared__ unsigned hcnt[NB], hb[NB], dlt[NB], hcur[NB];
    __shared__ unsigned sc[512];
    __shared__ int smode;

    const int t = threadIdx.x;
    if (t == 0) {
        unsigned orv = 0;
        for (int i = 0; i < 16; ++i) orv |= (unsigned)edges[2 * i + 1];
        smode = (orv == 0u) ? 1 : 0;  // 1 = int64
    }
    for (int i = t; i < NB; i += 256) { hcnt[i] = 0; hcur[i] = 0; }
    __syncthreads();
    const int m = smode;
    const int base_e = blockIdx.x * ACHUNK;
    const int total = min(ACHUNK, NE - base_e);

    // pass 1: load edges into registers, histogram buckets
    unsigned pay[AEPT];
    ushort_t bk[AEPT];
#pragma unroll
    for (int q = 0; q < AEPT; ++q) {
        int e = base_e + t + q * 256;
        pay[q] = 0;
        bk[q] = 0xffff;
        if (e < NE) {
            int d = load_dst(edges, m, e);
            int s = load_src(edges, m, e);
            pay[q] = ((unsigned)s << 8) | (unsigned)(d & 255);
            bk[q] = (ushort_t)(d >> 8);
            atomicAdd(&hcnt[d >> 8], 1u);
        }
    }
    __syncthreads();

    // global reservation per bucket
    for (int i = t; i < NB; i += 256) dlt[i] = atomicAdd(&bcur[i], hcnt[i]);  // hrun
    // block-level exclusive scan of hcnt -> hb
    sc[t] = (t < NB) ? hcnt[t] : 0u;
    sc[t + 256] = (t + 256 < NB) ? hcnt[t + 256] : 0u;
    __syncthreads();
    for (int ofs = 1; ofs < 512; ofs <<= 1) {
        unsigned v0 = (t >= ofs) ? sc[t - ofs] : 0u;
        unsigned v1 = (t + 256 >= ofs) ? sc[t + 256 - ofs] : 0u;
        __syncthreads();
        sc[t] += v0;
        sc[t + 256] += v1;
        __syncthreads();
    }
    for (int i = t; i < NB; i += 256) hb[i] = sc[i] - hcnt[i];
    __syncthreads();
    for (int i = t; i < NB; i += 256) dlt[i] = dlt[i] - hb[i];
    __syncthreads();

    // pass 2: rank into LDS-sorted order
#pragma unroll
    for (int q = 0; q < AEPT; ++q) {
        if (bk[q] != 0xffff) {
            unsigned b = bk[q];
            unsigned r = atomicAdd(&hcur[b], 1u);
            unsigned idx = hb[b] + r;
            pay_lds[idx] = pay[q];
            bkt_lds[idx] = (ushort_t)b;
        }
    }
    __syncthreads();

    // flush: coalesced within bucket runs
    for (int i = t; i < total; i += 256) {
        unsigned b = bkt_lds[i];
        unsigned within = (unsigned)i + dlt[b];
        if (within < BCAP)
            staged[(size_t)b * BCAP + within] = pay_lds[i];
    }
}

__global__ void k_bscan(const unsigned* __restrict__ bcur, unsigned* __restrict__ bbase) {
    __shared__ unsigned tmp[512];
    int t = threadIdx.x;
    unsigned x = (t < NB) ? bcur[t] : 0u;
    tmp[t] = x;
    __syncthreads();
    for (int ofs = 1; ofs < 512; ofs <<= 1) {
        unsigned v = (t >= ofs) ? tmp[t - ofs] : 0u;
        __syncthreads();
        tmp[t] += v;
        __syncthreads();
    }
    if (t < NB) bbase[t] = tmp[t] - x;
}

// ---- phase B: per-bucket counting sort -> rowstart + src-only CSR ----
__global__ __launch_bounds__(256) void k_phaseB(const unsigned* __restrict__ staged,
                                                const unsigned* __restrict__ bcur,
                                                const unsigned* __restrict__ bbase,
                                                unsigned* __restrict__ rowstart,
                                                int* __restrict__ esrc) {
    __shared__ unsigned hist[256], hb[256], hcur[256], tmp[256];
    const int b = blockIdx.x;
    const int t = threadIdx.x;
    const unsigned cnt = min(bcur[b], (unsigned)BCAP);
    const unsigned base = bbase[b];
    hist[t] = 0;
    hcur[t] = 0;
    __syncthreads();
    const unsigned* sb = staged + (size_t)b * BCAP;
    for (unsigned i = t; i < cnt; i += 256) atomicAdd(&hist[sb[i] & 255u], 1u);
    __syncthreads();
    unsigned x = hist[t];
    tmp[t] = x;
    __syncthreads();
    for (int ofs = 1; ofs < 256; ofs <<= 1) {
        unsigned v = (t >= ofs) ? tmp[t - ofs] : 0u;
        __syncthreads();
        tmp[t] += v;
        __syncthreads();
    }
    hb[t] = tmp[t] - x;
    int v = b * 256 + t;
    if (v <= NN) rowstart[v] = base + hb[t];
    __syncthreads();
    for (unsigned i = t; i < cnt; i += 256) {
        unsigned p = sb[i];
        unsigned dlo = p & 255u;
        unsigned pos = base + hb[dlo] + atomicAdd(&hcur[dlo], 1u);
        esrc[pos] = (int)(p >> 8);
    }
}

__global__ void k_dinv(const unsigned* __restrict__ rowstart, float* __restrict__ dinv) {
    int v = blockIdx.x * blockDim.x + threadIdx.x;
    if (v < NN) dinv[v] = rsqrtf((float)(1u + rowstart[v + 1] - rowstart[v]));
}

// ---- GEMM1 v3: MFMA bf16 16x16x32, no LDS. wave = 16 nodes x 64 cols ----
// k-map kappa(g,e) = g*8+e used identically for A and B fragments: result is
// invariant to the HW's internal k-permutation (same map on both operands).
__global__ __launch_bounds__(256) void k_gemm1(const float* __restrict__ x,
                                               const float* __restrict__ W,
                                               ushort_t* __restrict__ h) {
    const int tid = threadIdx.x;
    const int l = tid & 63;
    const int w = tid >> 6;
    const int m = l & 15;    // A row (node) / B col
    const int g = l >> 4;    // k-group
    const int node0 = blockIdx.x * 64 + w * 16;

    // B fragments from W1 [128][64] f32: bfrag[ks][nt][e] = bf16(W[ks*32+g*8+e][nt*16+m])
    bf16x8 bfrag[4][4];
#pragma unroll
    for (int ks = 0; ks < 4; ++ks)
#pragma unroll
        for (int nt = 0; nt < 4; ++nt)
#pragma unroll
            for (int e = 0; e < 8; ++e)
                bfrag[ks][nt][e] = (short)f2bf(W[(ks * 32 + g * 8 + e) * FH + nt * 16 + m]);

    f32x4 acc[4];
#pragma unroll
    for (int nt = 0; nt < 4; ++nt) acc[nt] = (f32x4){0.f, 0.f, 0.f, 0.f};

    int node = node0 + m;
    const float* xrow = x + (size_t)(node < NN ? node : NN - 1) * FI;
#pragma unroll
    for (int ks = 0; ks < 4; ++ks) {
        float4 xa = *(const float4*)&xrow[ks * 32 + g * 8];
        float4 xb = *(const float4*)&xrow[ks * 32 + g * 8 + 4];
        bf16x8 afrag;
        afrag[0] = (short)f2bf(xa.x);
        afrag[1] = (short)f2bf(xa.y);
        afrag[2] = (short)f2bf(xa.z);
        afrag[3] = (short)f2bf(xa.w);
        afrag[4] = (short)f2bf(xb.x);
        afrag[5] = (short)f2bf(xb.y);
        afrag[6] = (short)f2bf(xb.z);
        afrag[7] = (short)f2bf(xb.w);
#pragma unroll
        for (int nt = 0; nt < 4; ++nt)
            acc[nt] = __builtin_amdgcn_mfma_f32_16x16x32_bf16(afrag, bfrag[ks][nt], acc[nt], 0, 0, 0);
    }

    // D layout (verified m89): col = l&15, row = (l>>4)*4 + r
#pragma unroll
    for (int nt = 0; nt < 4; ++nt)
#pragma unroll
        for (int r = 0; r < 4; ++r) {
            int outnode = node0 + g * 4 + r;
            if (outnode < NN)
                h[(size_t)outnode * FH + nt * 16 + m] = f2bf(acc[nt][r]);
        }
}

// ---- fused layer1 aggregate + GEMM2: 4 nodes/wave, 16 lanes/node ----
__global__ __launch_bounds__(256) void k_gather1f(const unsigned* __restrict__ rowstart,
                                                  const int* __restrict__ esrc,
                                                  const ushort_t* __restrict__ h1p,
                                                  const float* __restrict__ dinv,
                                                  const float* __restrict__ b1,
                                                  const float* __restrict__ W2,
                                                  ushort_t* __restrict__ h2p) {
    __shared__ float Ws2t[FO][FH];  // Ws2t[j][k] = W2[k][j]
    {
        int t = threadIdx.x;
#pragma unroll
        for (int i = 0; i < 4; ++i) {
            int q = t * 4 + i;
            int k = q >> 4, j = q & 15;
            Ws2t[j][k] = W2[q];
        }
    }
    __syncthreads();

    int wave = (blockIdx.x * 256 + threadIdx.x) >> 6;
    int lane = threadIdx.x & 63;
    int grp = lane >> 4;
    int fj = lane & 15;
    int v = wave * 4 + grp;
    if (v >= NN) return;

    const uint2* h2v = (const uint2*)h1p;
    unsigned beg = rowstart[v], end = rowstart[v + 1];
    float dv = dinv[v];
    float a0 = 0.f, a1 = 0.f, a2 = 0.f, a3 = 0.f;
    unsigned i = beg;
    for (; i + 3 < end; i += 4) {
        int s0 = esrc[i], s1 = esrc[i + 1], s2 = esrc[i + 2], s3 = esrc[i + 3];
        float n0 = dinv[s0] * dv, n1 = dinv[s1] * dv;
        float n2 = dinv[s2] * dv, n3 = dinv[s3] * dv;
        uint2 u0 = h2v[(size_t)s0 * 16 + fj];
        uint2 u1 = h2v[(size_t)s1 * 16 + fj];
        uint2 u2 = h2v[(size_t)s2 * 16 + fj];
        uint2 u3 = h2v[(size_t)s3 * 16 + fj];
        a0 += bf_lo(u0.x) * n0 + bf_lo(u1.x) * n1 + bf_lo(u2.x) * n2 + bf_lo(u3.x) * n3;
        a1 += bf_hi(u0.x) * n0 + bf_hi(u1.x) * n1 + bf_hi(u2.x) * n2 + bf_hi(u3.x) * n3;
        a2 += bf_lo(u0.y) * n0 + bf_lo(u1.y) * n1 + bf_lo(u2.y) * n2 + bf_lo(u3.y) * n3;
        a3 += bf_hi(u0.y) * n0 + bf_hi(u1.y) * n1 + bf_hi(u2.y) * n2 + bf_hi(u3.y) * n3;
    }
    for (; i < end; ++i) {
        int s = esrc[i];
        float n = dinv[s] * dv;
        uint2 u = h2v[(size_t)s * 16 + fj];
        a0 += bf_lo(u.x) * n;
        a1 += bf_hi(u.x) * n;
        a2 += bf_lo(u.y) * n;
        a3 += bf_hi(u.y) * n;
    }
    float di2 = dv * dv;
    uint2 us = h2v[(size_t)v * 16 + fj];
    float4 bb = ((const float4*)b1)[fj];
    float r0 = fmaxf(a0 + bf_lo(us.x) * di2 + bb.x, 0.f);
    float r1 = fmaxf(a1 + bf_hi(us.x) * di2 + bb.y, 0.f);
    float r2 = fmaxf(a2 + bf_lo(us.y) * di2 + bb.z, 0.f);
    float r3 = fmaxf(a3 + bf_hi(us.y) * di2 + bb.w, 0.f);

    float p[16];
#pragma unroll
    for (int j = 0; j < 16; ++j) {
        float4 w = *(const float4*)&Ws2t[j][fj * 4];
        p[j] = r0 * w.x + r1 * w.y + r2 * w.z + r3 * w.w;
    }
    bool c0 = (fj & 1) != 0;
    float q8[8];
#pragma unroll
    for (int k = 0; k < 8; ++k) {
        float sent = c0 ? p[2 * k] : p[2 * k + 1];
        float kept = c0 ? p[2 * k + 1] : p[2 * k];
        q8[k] = kept + __shfl_xor(sent, 1);
    }
    bool c1 = (fj & 2) != 0;
    float q4[4];
#pragma unroll
    for (int k = 0; k < 4; ++k) {
        float sent = c1 ? q8[2 * k] : q8[2 * k + 1];
        float kept = c1 ? q8[2 * k + 1] : q8[2 * k];
        q4[k] = kept + __shfl_xor(sent, 2);
    }
    bool c2 = (fj & 4) != 0;
    float q2[2];
#pragma unroll
    for (int k = 0; k < 2; ++k) {
        float sent = c2 ? q4[2 * k] : q4[2 * k + 1];
        float kept = c2 ? q4[2 * k + 1] : q4[2 * k];
        q2[k] = kept + __shfl_xor(sent, 4);
    }
    bool c3 = (fj & 8) != 0;
    {
        float sent = c3 ? q2[0] : q2[1];
        float kept = c3 ? q2[1] : q2[0];
        float fin = kept + __shfl_xor(sent, 8);
        h2p[(size_t)v * FO + fj] = f2bf(fin);
    }
}

// ---- layer2 aggregate: 4 nodes/wave, 16 lanes/node, 1 feat/lane, unroll 4 ----
__global__ __launch_bounds__(256) void k_gather2(const unsigned* __restrict__ rowstart,
                                                 const int* __restrict__ esrc,
                                                 const ushort_t* __restrict__ h2p,
                                                 const float* __restrict__ dinv,
                                                 const float* __restrict__ b,
                                                 float* __restrict__ out) {
    int wave = (blockIdx.x * 256 + threadIdx.x) >> 6;
    int lane = threadIdx.x & 63;
    int grp = lane >> 4;
    int j = lane & 15;
    int v = wave * 4 + grp;
    if (v >= NN) return;
    unsigned beg = rowstart[v], end = rowstart[v + 1];
    float dv = dinv[v];
    float acc = 0.f;
    unsigned i = beg;
    for (; i + 3 < end; i += 4) {
        int s0 = esrc[i], s1 = esrc[i + 1], s2 = esrc[i + 2], s3 = esrc[i + 3];
        float n0 = dinv[s0] * dv, n1 = dinv[s1] * dv;
        float n2 = dinv[s2] * dv, n3 = dinv[s3] * dv;
        float x0 = __uint_as_float((unsigned)h2p[(size_t)s0 * FO + j] << 16);
        float x1 = __uint_as_float((unsigned)h2p[(size_t)s1 * FO + j] << 16);
        float x2 = __uint_as_float((unsigned)h2p[(size_t)s2 * FO + j] << 16);
        float x3 = __uint_as_float((unsigned)h2p[(size_t)s3 * FO + j] << 16);
        acc += x0 * n0 + x1 * n1 + x2 * n2 + x3 * n3;
    }
    for (; i < end; ++i) {
        int s = esrc[i];
        acc += __uint_as_float((unsigned)h2p[(size_t)s * FO + j] << 16) * (dinv[s] * dv);
    }
    float val = acc + __uint_as_float((unsigned)h2p[(size_t)v * FO + j] << 16) * dv * dv + b[j];
    float m = val;
#pragma unroll
    for (int w = 1; w < 16; w <<= 1) m = fmaxf(m, __shfl_xor(m, w));
    float ex = expf(val - m);
    float ssum = ex;
#pragma unroll
    for (int w = 1; w < 16; w <<= 1) ssum += __shfl_xor(ssum, w);
    float res = val - (m + logf(ssum));
    out[(size_t)v * FO + j] = res;
}

extern "C" void kernel_launch(void* const* d_in, const int* in_sizes, int n_in,
                              void* d_out, int out_size, void* d_ws, size_t ws_size,
                              hipStream_t stream) {
    const float* x = (const float*)d_in[0];
    const int* edges = (const int*)d_in[1];
    const float* W1 = (const float*)d_in[2];
    const float* b1 = (const float*)d_in[3];
    const float* W2 = (const float*)d_in[4];
    const float* b2 = (const float*)d_in[5];
    float* out = (float*)d_out;

    char* ws = (char*)d_ws;
    size_t off = 0;
    auto take = [&](size_t bytes) {
        void* p = ws + off;
        off += (bytes + 255) & ~(size_t)255;
        return p;
    };
    unsigned* bcur = (unsigned*)take((size_t)NB * 4);
    unsigned* bbase = (unsigned*)take((size_t)NB * 4);
    unsigned* rowstart = (unsigned*)take((size_t)(NN + 1) * 4);
    float* dinv = (float*)take((size_t)NN * 4);
    int* esrc = (int*)take((size_t)NE * 4);
    ushort_t* h1p = (ushort_t*)take((size_t)NN * FH * 2);   // bf16
    ushort_t* h2p = (ushort_t*)take((size_t)NN * FO * 2);   // bf16
    unsigned* staged = (unsigned*)take((size_t)NB * BCAP * 4);  // 8.8 MB

    hipMemsetAsync(bcur, 0, (size_t)NB * 4, stream);
    k_phaseA<<<ABLK, 256, 0, stream>>>(edges, bcur, staged);
    k_bscan<<<1, 512, 0, stream>>>(bcur, bbase);
    k_phaseB<<<NB, 256, 0, stream>>>(staged, bcur, bbase, rowstart, esrc);
    k_dinv<<<(NN + 255) / 256, 256, 0, stream>>>(rowstart, dinv);
    k_gemm1<<<(NN + 63) / 64, 256, 0, stream>>>(x, W1, h1p);
    k_gather1f<<<(NN + 15) / 16, 256, 0, stream>>>(rowstart, esrc, h1p, dinv, b1, W2, h2p);
    k_gather2<<<(NN + 15) / 16, 256, 0, stream>>>(rowstart, esrc, h2p, dinv, b2, out);
}

// Round 12
// 113.921 us; speedup vs baseline: 5.8112x; 1.1822x over previous
//
#include <hip/hip_runtime.h>
#include <math.h>

#define NN 100000
#define NE 1600000
#define FI 128
#define FH 64
#define FO 16
#define NB 392            // buckets of 256 nodes
#define BCAP 5632
#define AEPT 16
#define ACHUNK (256 * AEPT)                 // 4096 edges per phase-A block
#define ABLK ((NE + ACHUNK - 1) / ACHUNK)   // 391
#define GBLK ((NN + 63) / 64)               // 1563 gemm1 blocks

typedef unsigned short ushort_t;
typedef __attribute__((ext_vector_type(8))) short bf16x8;
typedef __attribute__((ext_vector_type(4))) float f32x4;

__device__ __forceinline__ ushort_t f2bf(float f) {
    unsigned u = __float_as_uint(f);
    u = (u + 0x7fffu + ((u >> 16) & 1u)) >> 16;  // RNE
    return (ushort_t)u;
}
__device__ __forceinline__ float bf_lo(unsigned u) {
    return __uint_as_float(u << 16);
}
__device__ __forceinline__ float bf_hi(unsigned u) {
    return __uint_as_float(u & 0xffff0000u);
}

__device__ __forceinline__ int load_dst(const int* edges, int mode, int e) {
    return mode ? edges[2 * (NE + e)] : edges[NE + e];
}
__device__ __forceinline__ int load_src(const int* edges, int mode, int e) {
    return mode ? edges[2 * e] : edges[e];
}

// ---- fused: blocks [0,ABLK) = phaseA edge sort; blocks [ABLK,..) = gemm1 MFMA ----
__global__ __launch_bounds__(256) void k_fuseA(const int* __restrict__ edges,
                                               unsigned* __restrict__ bcur,
                                               unsigned* __restrict__ staged,
                                               const float* __restrict__ x,
                                               const float* __restrict__ W1,
                                               ushort_t* __restrict__ h1p) {
    __shared__ unsigned pay_lds[ACHUNK];       // 16 KB
    __shared__ ushort_t bkt_lds[ACHUNK];       // 8 KB
    __shared__ unsigned hcnt[NB], hb[NB], dlt[NB], hcur[NB];
    __shared__ unsigned sc[512];
    __shared__ int smode;

    if (blockIdx.x >= ABLK) {
        // ================= gemm1: MFMA bf16 16x16x32, no LDS =================
        const int tid = threadIdx.x;
        const int l = tid & 63;
        const int w = tid >> 6;
        const int m = l & 15;
        const int g = l >> 4;
        const int node0 = (blockIdx.x - ABLK) * 64 + w * 16;

        bf16x8 bfrag[4][4];
#pragma unroll
        for (int ks = 0; ks < 4; ++ks)
#pragma unroll
            for (int nt = 0; nt < 4; ++nt)
#pragma unroll
                for (int e = 0; e < 8; ++e)
                    bfrag[ks][nt][e] = (short)f2bf(W1[(ks * 32 + g * 8 + e) * FH + nt * 16 + m]);

        f32x4 acc[4];
#pragma unroll
        for (int nt = 0; nt < 4; ++nt) acc[nt] = (f32x4){0.f, 0.f, 0.f, 0.f};

        int node = node0 + m;
        const float* xrow = x + (size_t)(node < NN ? node : NN - 1) * FI;
#pragma unroll
        for (int ks = 0; ks < 4; ++ks) {
            float4 xa = *(const float4*)&xrow[ks * 32 + g * 8];
            float4 xb = *(const float4*)&xrow[ks * 32 + g * 8 + 4];
            bf16x8 afrag;
            afrag[0] = (short)f2bf(xa.x);
            afrag[1] = (short)f2bf(xa.y);
            afrag[2] = (short)f2bf(xa.z);
            afrag[3] = (short)f2bf(xa.w);
            afrag[4] = (short)f2bf(xb.x);
            afrag[5] = (short)f2bf(xb.y);
            afrag[6] = (short)f2bf(xb.z);
            afrag[7] = (short)f2bf(xb.w);
#pragma unroll
            for (int nt = 0; nt < 4; ++nt)
                acc[nt] = __builtin_amdgcn_mfma_f32_16x16x32_bf16(afrag, bfrag[ks][nt], acc[nt], 0, 0, 0);
        }
#pragma unroll
        for (int nt = 0; nt < 4; ++nt)
#pragma unroll
            for (int r = 0; r < 4; ++r) {
                int outnode = node0 + g * 4 + r;
                if (outnode < NN)
                    h1p[(size_t)outnode * FH + nt * 16 + m] = f2bf(acc[nt][r]);
            }
        return;
    }

    // ================= phaseA: LDS counting sort, coalesced flush =================
    const int t = threadIdx.x;
    if (t == 0) {
        unsigned orv = 0;
        for (int i = 0; i < 16; ++i) orv |= (unsigned)edges[2 * i + 1];
        smode = (orv == 0u) ? 1 : 0;  // 1 = int64
    }
    for (int i = t; i < NB; i += 256) { hcnt[i] = 0; hcur[i] = 0; }
    __syncthreads();
    const int m = smode;
    const int base_e = blockIdx.x * ACHUNK;
    const int total = min(ACHUNK, NE - base_e);

    unsigned pay[AEPT];
    ushort_t bk[AEPT];
#pragma unroll
    for (int q = 0; q < AEPT; ++q) {
        int e = base_e + t + q * 256;
        pay[q] = 0;
        bk[q] = 0xffff;
        if (e < NE) {
            int d = load_dst(edges, m, e);
            int s = load_src(edges, m, e);
            pay[q] = ((unsigned)s << 8) | (unsigned)(d & 255);
            bk[q] = (ushort_t)(d >> 8);
            atomicAdd(&hcnt[d >> 8], 1u);
        }
    }
    __syncthreads();

    for (int i = t; i < NB; i += 256) dlt[i] = atomicAdd(&bcur[i], hcnt[i]);  // hrun
    sc[t] = (t < NB) ? hcnt[t] : 0u;
    sc[t + 256] = (t + 256 < NB) ? hcnt[t + 256] : 0u;
    __syncthreads();
    for (int ofs = 1; ofs < 512; ofs <<= 1) {
        unsigned v0 = (t >= ofs) ? sc[t - ofs] : 0u;
        unsigned v1 = (t + 256 >= ofs) ? sc[t + 256 - ofs] : 0u;
        __syncthreads();
        sc[t] += v0;
        sc[t + 256] += v1;
        __syncthreads();
    }
    for (int i = t; i < NB; i += 256) hb[i] = sc[i] - hcnt[i];
    __syncthreads();
    for (int i = t; i < NB; i += 256) dlt[i] = dlt[i] - hb[i];
    __syncthreads();

#pragma unroll
    for (int q = 0; q < AEPT; ++q) {
        if (bk[q] != 0xffff) {
            unsigned b = bk[q];
            unsigned r = atomicAdd(&hcur[b], 1u);
            unsigned idx = hb[b] + r;
            pay_lds[idx] = pay[q];
            bkt_lds[idx] = (ushort_t)b;
        }
    }
    __syncthreads();

    for (int i = t; i < total; i += 256) {
        unsigned b = bkt_lds[i];
        unsigned within = (unsigned)i + dlt[b];
        if (within < BCAP)
            staged[(size_t)b * BCAP + within] = pay_lds[i];
    }
}

// ---- phase B: bucket-base scan + per-bucket counting sort + dinv ----
__global__ __launch_bounds__(256) void k_phaseB(const unsigned* __restrict__ staged,
                                                const unsigned* __restrict__ bcur,
                                                unsigned* __restrict__ rowstart,
                                                int* __restrict__ esrc,
                                                float* __restrict__ dinv) {
    __shared__ unsigned hist[256], hb[256], hcur[256], tmp[256];
    __shared__ unsigned sbc[512];
    const int b = blockIdx.x;
    const int t = threadIdx.x;

    // in-block scan of bcur -> this bucket's base (inclusive scan, take sbc[b-1])
    sbc[t] = (t < NB) ? bcur[t] : 0u;
    sbc[t + 256] = (t + 256 < NB) ? bcur[t + 256] : 0u;
    __syncthreads();
    for (int ofs = 1; ofs < 512; ofs <<= 1) {
        unsigned v0 = (t >= ofs) ? sbc[t - ofs] : 0u;
        unsigned v1 = (t + 256 >= ofs) ? sbc[t + 256 - ofs] : 0u;
        __syncthreads();
        sbc[t] += v0;
        sbc[t + 256] += v1;
        __syncthreads();
    }
    const unsigned base = (b == 0) ? 0u : sbc[b - 1];
    const unsigned cnt = min(bcur[b], (unsigned)BCAP);

    hist[t] = 0;
    hcur[t] = 0;
    __syncthreads();
    const unsigned* sb = staged + (size_t)b * BCAP;
    for (unsigned i = t; i < cnt; i += 256) atomicAdd(&hist[sb[i] & 255u], 1u);
    __syncthreads();
    unsigned x = hist[t];
    tmp[t] = x;
    __syncthreads();
    for (int ofs = 1; ofs < 256; ofs <<= 1) {
        unsigned v = (t >= ofs) ? tmp[t - ofs] : 0u;
        __syncthreads();
        tmp[t] += v;
        __syncthreads();
    }
    hb[t] = tmp[t] - x;
    int v = b * 256 + t;
    if (v <= NN) rowstart[v] = base + hb[t];
    if (v < NN) dinv[v] = rsqrtf((float)(1u + x));
    __syncthreads();
    for (unsigned i = t; i < cnt; i += 256) {
        unsigned p = sb[i];
        unsigned dlo = p & 255u;
        unsigned pos = base + hb[dlo] + atomicAdd(&hcur[dlo], 1u);
        esrc[pos] = (int)(p >> 8);
    }
}

// ---- fused layer1 aggregate + GEMM2: 4 nodes/wave, 16 lanes/node, esrc prefetch ----
__global__ __launch_bounds__(256) void k_gather1f(const unsigned* __restrict__ rowstart,
                                                  const int* __restrict__ esrc,
                                                  const ushort_t* __restrict__ h1p,
                                                  const float* __restrict__ dinv,
                                                  const float* __restrict__ b1,
                                                  const float* __restrict__ W2,
                                                  ushort_t* __restrict__ h2p) {
    __shared__ float Ws2t[FO][FH];  // Ws2t[j][k] = W2[k][j]
    {
        int t = threadIdx.x;
#pragma unroll
        for (int i = 0; i < 4; ++i) {
            int q = t * 4 + i;
            int k = q >> 4, j = q & 15;
            Ws2t[j][k] = W2[q];
        }
    }
    __syncthreads();

    int wave = (blockIdx.x * 256 + threadIdx.x) >> 6;
    int lane = threadIdx.x & 63;
    int grp = lane >> 4;
    int fj = lane & 15;
    int v = wave * 4 + grp;
    if (v >= NN) return;

    const uint2* h2v = (const uint2*)h1p;
    unsigned beg = rowstart[v], end = rowstart[v + 1];
    float dv = dinv[v];
    float a0 = 0.f, a1 = 0.f, a2 = 0.f, a3 = 0.f;
    unsigned i = beg;
    int ns0 = 0, ns1 = 0, ns2 = 0, ns3 = 0;
    if (i + 3 < end) { ns0 = esrc[i]; ns1 = esrc[i + 1]; ns2 = esrc[i + 2]; ns3 = esrc[i + 3]; }
    while (i + 3 < end) {
        int s0 = ns0, s1 = ns1, s2 = ns2, s3 = ns3;
        unsigned nx = i + 4;
        if (nx + 3 < end) { ns0 = esrc[nx]; ns1 = esrc[nx + 1]; ns2 = esrc[nx + 2]; ns3 = esrc[nx + 3]; }
        float n0 = dinv[s0] * dv, n1 = dinv[s1] * dv;
        float n2 = dinv[s2] * dv, n3 = dinv[s3] * dv;
        uint2 u0 = h2v[(size_t)s0 * 16 + fj];
        uint2 u1 = h2v[(size_t)s1 * 16 + fj];
        uint2 u2 = h2v[(size_t)s2 * 16 + fj];
        uint2 u3 = h2v[(size_t)s3 * 16 + fj];
        a0 += bf_lo(u0.x) * n0 + bf_lo(u1.x) * n1 + bf_lo(u2.x) * n2 + bf_lo(u3.x) * n3;
        a1 += bf_hi(u0.x) * n0 + bf_hi(u1.x) * n1 + bf_hi(u2.x) * n2 + bf_hi(u3.x) * n3;
        a2 += bf_lo(u0.y) * n0 + bf_lo(u1.y) * n1 + bf_lo(u2.y) * n2 + bf_lo(u3.y) * n3;
        a3 += bf_hi(u0.y) * n0 + bf_hi(u1.y) * n1 + bf_hi(u2.y) * n2 + bf_hi(u3.y) * n3;
        i = nx;
    }
    for (; i < end; ++i) {
        int s = esrc[i];
        float n = dinv[s] * dv;
        uint2 u = h2v[(size_t)s * 16 + fj];
        a0 += bf_lo(u.x) * n;
        a1 += bf_hi(u.x) * n;
        a2 += bf_lo(u.y) * n;
        a3 += bf_hi(u.y) * n;
    }
    float di2 = dv * dv;
    uint2 us = h2v[(size_t)v * 16 + fj];
    float4 bb = ((const float4*)b1)[fj];
    float r0 = fmaxf(a0 + bf_lo(us.x) * di2 + bb.x, 0.f);
    float r1 = fmaxf(a1 + bf_hi(us.x) * di2 + bb.y, 0.f);
    float r2 = fmaxf(a2 + bf_lo(us.y) * di2 + bb.z, 0.f);
    float r3 = fmaxf(a3 + bf_hi(us.y) * di2 + bb.w, 0.f);

    float p[16];
#pragma unroll
    for (int j = 0; j < 16; ++j) {
        float4 w = *(const float4*)&Ws2t[j][fj * 4];
        p[j] = r0 * w.x + r1 * w.y + r2 * w.z + r3 * w.w;
    }
    bool c0 = (fj & 1) != 0;
    float q8[8];
#pragma unroll
    for (int k = 0; k < 8; ++k) {
        float sent = c0 ? p[2 * k] : p[2 * k + 1];
        float kept = c0 ? p[2 * k + 1] : p[2 * k];
        q8[k] = kept + __shfl_xor(sent, 1);
    }
    bool c1 = (fj & 2) != 0;
    float q4[4];
#pragma unroll
    for (int k = 0; k < 4; ++k) {
        float sent = c1 ? q8[2 * k] : q8[2 * k + 1];
        float kept = c1 ? q8[2 * k + 1] : q8[2 * k];
        q4[k] = kept + __shfl_xor(sent, 2);
    }
    bool c2 = (fj & 4) != 0;
    float q2[2];
#pragma unroll
    for (int k = 0; k < 2; ++k) {
        float sent = c2 ? q4[2 * k] : q4[2 * k + 1];
        float kept = c2 ? q4[2 * k + 1] : q4[2 * k];
        q2[k] = kept + __shfl_xor(sent, 4);
    }
    bool c3 = (fj & 8) != 0;
    {
        float sent = c3 ? q2[0] : q2[1];
        float kept = c3 ? q2[1] : q2[0];
        float fin = kept + __shfl_xor(sent, 8);
        h2p[(size_t)v * FO + fj] = f2bf(fin);
    }
}

// ---- layer2 aggregate: 4 nodes/wave, 16 lanes/node, 1 feat/lane, esrc prefetch ----
__global__ __launch_bounds__(256) void k_gather2(const unsigned* __restrict__ rowstart,
                                                 const int* __restrict__ esrc,
                                                 const ushort_t* __restrict__ h2p,
                                                 const float* __restrict__ dinv,
                                                 const float* __restrict__ b,
                                                 float* __restrict__ out) {
    int wave = (blockIdx.x * 256 + threadIdx.x) >> 6;
    int lane = threadIdx.x & 63;
    int grp = lane >> 4;
    int j = lane & 15;
    int v = wave * 4 + grp;
    if (v >= NN) return;
    unsigned beg = rowstart[v], end = rowstart[v + 1];
    float dv = dinv[v];
    float acc = 0.f;
    unsigned i = beg;
    int ns0 = 0, ns1 = 0, ns2 = 0, ns3 = 0;
    if (i + 3 < end) { ns0 = esrc[i]; ns1 = esrc[i + 1]; ns2 = esrc[i + 2]; ns3 = esrc[i + 3]; }
    while (i + 3 < end) {
        int s0 = ns0, s1 = ns1, s2 = ns2, s3 = ns3;
        unsigned nx = i + 4;
        if (nx + 3 < end) { ns0 = esrc[nx]; ns1 = esrc[nx + 1]; ns2 = esrc[nx + 2]; ns3 = esrc[nx + 3]; }
        float n0 = dinv[s0] * dv, n1 = dinv[s1] * dv;
        float n2 = dinv[s2] * dv, n3 = dinv[s3] * dv;
        float x0 = __uint_as_float((unsigned)h2p[(size_t)s0 * FO + j] << 16);
        float x1 = __uint_as_float((unsigned)h2p[(size_t)s1 * FO + j] << 16);
        float x2 = __uint_as_float((unsigned)h2p[(size_t)s2 * FO + j] << 16);
        float x3 = __uint_as_float((unsigned)h2p[(size_t)s3 * FO + j] << 16);
        acc += x0 * n0 + x1 * n1 + x2 * n2 + x3 * n3;
        i = nx;
    }
    for (; i < end; ++i) {
        int s = esrc[i];
        acc += __uint_as_float((unsigned)h2p[(size_t)s * FO + j] << 16) * (dinv[s] * dv);
    }
    float val = acc + __uint_as_float((unsigned)h2p[(size_t)v * FO + j] << 16) * dv * dv + b[j];
    float m = val;
#pragma unroll
    for (int w = 1; w < 16; w <<= 1) m = fmaxf(m, __shfl_xor(m, w));
    float ex = expf(val - m);
    float ssum = ex;
#pragma unroll
    for (int w = 1; w < 16; w <<= 1) ssum += __shfl_xor(ssum, w);
    float res = val - (m + logf(ssum));
    out[(size_t)v * FO + j] = res;
}

extern "C" void kernel_launch(void* const* d_in, const int* in_sizes, int n_in,
                              void* d_out, int out_size, void* d_ws, size_t ws_size,
                              hipStream_t stream) {
    const float* x = (const float*)d_in[0];
    const int* edges = (const int*)d_in[1];
    const float* W1 = (const float*)d_in[2];
    const float* b1 = (const float*)d_in[3];
    const float* W2 = (const float*)d_in[4];
    const float* b2 = (const float*)d_in[5];
    float* out = (float*)d_out;

    char* ws = (char*)d_ws;
    size_t off = 0;
    auto take = [&](size_t bytes) {
        void* p = ws + off;
        off += (bytes + 255) & ~(size_t)255;
        return p;
    };
    unsigned* bcur = (unsigned*)take((size_t)NB * 4);
    unsigned* rowstart = (unsigned*)take((size_t)(NN + 1) * 4);
    float* dinv = (float*)take((size_t)NN * 4);
    int* esrc = (int*)take((size_t)NE * 4);
    ushort_t* h1p = (ushort_t*)take((size_t)NN * FH * 2);   // bf16
    ushort_t* h2p = (ushort_t*)take((size_t)NN * FO * 2);   // bf16
    unsigned* staged = (unsigned*)take((size_t)NB * BCAP * 4);  // 8.8 MB

    hipMemsetAsync(bcur, 0, (size_t)NB * 4, stream);
    k_fuseA<<<ABLK + GBLK, 256, 0, stream>>>(edges, bcur, staged, x, W1, h1p);
    k_phaseB<<<NB, 256, 0, stream>>>(staged, bcur, rowstart, esrc, dinv);
    k_gather1f<<<(NN + 15) / 16, 256, 0, stream>>>(rowstart, esrc, h1p, dinv, b1, W2, h2p);
    k_gather2<<<(NN + 15) / 16, 256, 0, stream>>>(rowstart, esrc, h2p, dinv, b2, out);
}